// Round 1
// baseline (985.481 us; speedup 1.0000x reference)
//
#include <hip/hip_runtime.h>
#include <cstdint>
#include <cstddef>

// ---------------- problem constants ----------------
#define TTOK 8192          // B*S tokens
#define HDIM 1024
#define IDIM 4096
#define NEXP 8
#define PMAX 17408         // 16384 + 8*128 (segment padding to 128)
#define MT_MAX 136         // PMAX/128 tiles max
#define WS_NEED 293871744ULL

typedef __attribute__((ext_vector_type(8))) short bf16x8;
typedef __attribute__((ext_vector_type(4))) float f32x4;

#define AS3 __attribute__((address_space(3)))
#define AS1 __attribute__((address_space(1)))

__device__ __forceinline__ void gld16(const void* g, void* s) {
  // async global->LDS, 16B/lane; LDS dest is wave-uniform base (+lane*16 in HW)
  __builtin_amdgcn_global_load_lds((const AS1 void*)g, (AS3 void*)s, 16, 0, 0);
}

__device__ __forceinline__ unsigned short f2b(float f) {
  unsigned u = __builtin_bit_cast(unsigned, f);
  unsigned r = ((u >> 16) & 1u) + 0x7FFFu;   // RNE
  return (unsigned short)((u + r) >> 16);
}

// meta layout (ints): [0..7] counts, [8..15] slots, [16..24] offs, meta[24]=padded total
// ---------------- router: logits, top2, x->bf16 ----------------
__global__ __launch_bounds__(256, 2) void router_k(
    const float* __restrict__ x, const float* __restrict__ wr,
    unsigned short* __restrict__ xb, int* __restrict__ t2e,
    float* __restrict__ t2w, int* __restrict__ meta)
{
  const int t = blockIdx.x * 4 + (threadIdx.x >> 6);
  const int l = threadIdx.x & 63;
  const float* xr = x + (size_t)t * HDIM;
  float acc[8] = {0.f,0.f,0.f,0.f,0.f,0.f,0.f,0.f};
  #pragma unroll
  for (int j = 0; j < 4; ++j) {
    const int base = j * 256 + l * 4;
    const float4 xv = *(const float4*)(xr + base);
    const float xa[4] = {xv.x, xv.y, xv.z, xv.w};
    ushort4 ub;
    ub.x = f2b(xa[0]); ub.y = f2b(xa[1]); ub.z = f2b(xa[2]); ub.w = f2b(xa[3]);
    *(ushort4*)(xb + (size_t)t * HDIM + base) = ub;
    #pragma unroll
    for (int ii = 0; ii < 4; ++ii) {
      const float4 w0 = *(const float4*)(wr + (size_t)(base + ii) * 8);
      const float4 w1 = *(const float4*)(wr + (size_t)(base + ii) * 8 + 4);
      acc[0] += xa[ii] * w0.x; acc[1] += xa[ii] * w0.y;
      acc[2] += xa[ii] * w0.z; acc[3] += xa[ii] * w0.w;
      acc[4] += xa[ii] * w1.x; acc[5] += xa[ii] * w1.y;
      acc[6] += xa[ii] * w1.z; acc[7] += xa[ii] * w1.w;
    }
  }
  #pragma unroll
  for (int e = 0; e < 8; ++e) {
    float v = acc[e];
    #pragma unroll
    for (int off = 32; off > 0; off >>= 1) v += __shfl_xor(v, off);
    acc[e] = v;
  }
  if (l == 0) {
    float l0 = -1e30f; int i0 = 0;
    #pragma unroll
    for (int e = 0; e < 8; ++e) if (acc[e] > l0) { l0 = acc[e]; i0 = e; }
    float l1 = -1e30f; int i1 = (i0 == 0) ? 1 : 0;
    #pragma unroll
    for (int e = 0; e < 8; ++e) if (e != i0 && acc[e] > l1) { l1 = acc[e]; i1 = e; }
    // renormalized top2 softmax == sigmoid of gap
    const float w0 = 1.f / (1.f + expf(l1 - l0));
    t2e[t * 2] = i0; t2e[t * 2 + 1] = i1;
    t2w[t * 2] = w0; t2w[t * 2 + 1] = 1.f - w0;
    atomicAdd(&meta[i0], 1); atomicAdd(&meta[i1], 1);
  }
}

// ---------------- offsets (1 thread) ----------------
__global__ void offsets_k(int* meta) {
  if (threadIdx.x == 0 && blockIdx.x == 0) {
    int off = 0;
    #pragma unroll
    for (int e = 0; e < 8; ++e) { meta[16 + e] = off; off += (meta[e] + 127) & ~127; }
    meta[24] = off;
  }
}

__global__ void initlist_k(int* __restrict__ ltok, float* __restrict__ lw) {
  const int i = blockIdx.x * 256 + threadIdx.x;
  ltok[i] = -1; lw[i] = 0.f;
}

__global__ void fill_k(const int* __restrict__ t2e, const float* __restrict__ t2w,
                       int* __restrict__ meta, int* __restrict__ ltok,
                       float* __restrict__ lw)
{
  const int t = blockIdx.x * 256 + threadIdx.x;
  #pragma unroll
  for (int k = 0; k < 2; ++k) {
    const int e = t2e[t * 2 + k];
    const float wv = t2w[t * 2 + k];
    const int p = atomicAdd(&meta[8 + e], 1);
    const int pos = meta[16 + e] + p;
    ltok[pos] = t; lw[pos] = wv;
  }
}

// ---------------- transpose-pack W[e][K][N] fp32 -> WT[e][N][K] bf16 ----------------
__global__ __launch_bounds__(256, 2) void packT_k(const float* __restrict__ src,
                                                  unsigned short* __restrict__ dst,
                                                  int K, int N)
{
  const int tiles_n = N >> 8, tiles_k = K >> 5;
  const int bid = blockIdx.x;
  const int e = bid / (tiles_k * tiles_n);
  const int rem = bid % (tiles_k * tiles_n);
  const int kt = rem / tiles_n, it = rem % tiles_n;
  const float* S = src + (size_t)e * K * N + (size_t)kt * 32 * N + (size_t)it * 256;
  unsigned short* D = dst + (size_t)e * N * K + (size_t)it * 256 * K + (size_t)kt * 32;
  __shared__ uint32_t lds[256 * 17];
  const int t = threadIdx.x;
  #pragma unroll
  for (int q = 0; q < 4; ++q) {
    const int task = q * 256 + t;
    const int i4 = task & 63, kp = task >> 6;
    const float* p0 = S + (size_t)(2 * kp) * N + i4 * 4;
    const float4 r0 = *(const float4*)p0;
    const float4 r1 = *(const float4*)(p0 + N);
    const float a0[4] = {r0.x, r0.y, r0.z, r0.w};
    const float a1[4] = {r1.x, r1.y, r1.z, r1.w};
    #pragma unroll
    for (int j = 0; j < 4; ++j)
      lds[(i4 * 4 + j) * 17 + kp] = (uint32_t)f2b(a0[j]) | ((uint32_t)f2b(a1[j]) << 16);
  }
  __syncthreads();
  #pragma unroll
  for (int r = 0; r < 4; ++r) {
    const int idx = r * 256 + t;
    const int il = idx >> 2, q4 = idx & 3;
    uint4 o;
    o.x = lds[il * 17 + q4 * 4 + 0];
    o.y = lds[il * 17 + q4 * 4 + 1];
    o.z = lds[il * 17 + q4 * 4 + 2];
    o.w = lds[il * 17 + q4 * 4 + 3];
    *(uint4*)(D + (size_t)il * K + q4 * 8) = o;
  }
}

// ---------------- grouped GEMM1: h = silu(Xg @ W1T^T + b1), bf16 out ----------------
__global__ __launch_bounds__(256, 2) void gemm1_k(
    const unsigned short* __restrict__ xb, const unsigned short* __restrict__ w1t,
    const float* __restrict__ b1, const int* __restrict__ meta,
    const int* __restrict__ ltok, unsigned short* __restrict__ h)
{
  const int mt = blockIdx.x, nt = blockIdx.y;
  if (mt * 128 >= meta[24]) return;
  int e = 0;
  #pragma unroll
  for (int i = 1; i < 8; ++i) if (meta[16 + i] <= mt * 128) e = i;

  __shared__ unsigned short As[128 * 32];
  __shared__ unsigned short Bs[128 * 32];
  const int t = threadIdx.x;
  const int w = t >> 6, l = t & 63;
  const int wm = w & 1, wn = w >> 1;
  const int r0 = t >> 2, c8 = (t & 3) * 8;

  int tok0 = ltok[mt * 128 + r0];       if (tok0 < 0) tok0 = 0;
  int tok1 = ltok[mt * 128 + 64 + r0];  if (tok1 < 0) tok1 = 0;
  const unsigned short* a0 = xb + (size_t)tok0 * HDIM + c8;
  const unsigned short* a1 = xb + (size_t)tok1 * HDIM + c8;
  const unsigned short* bp0 = w1t + ((size_t)e * IDIM + nt * 128 + r0) * HDIM + c8;
  const unsigned short* bp1 = bp0 + (size_t)64 * HDIM;

  unsigned short* sA0 = As + w * 512;            // wave-uniform dests
  unsigned short* sA1 = As + 2048 + w * 512;
  unsigned short* sB0 = Bs + w * 512;
  unsigned short* sB1 = Bs + 2048 + w * 512;

  const int lr = l & 15, lc = (l >> 4) * 8;
  const unsigned short* arp = As + (wm * 64 + lr) * 32 + lc;
  const unsigned short* brp = Bs + (wn * 64 + lr) * 32 + lc;

  f32x4 acc[4][4] = {};
  for (int ks = 0; ks < HDIM; ks += 32) {
    gld16(a0 + ks, sA0);
    gld16(a1 + ks, sA1);
    gld16(bp0 + ks, sB0);
    gld16(bp1 + ks, sB1);
    __syncthreads();
    bf16x8 af[4], bfr[4];
    #pragma unroll
    for (int fm = 0; fm < 4; ++fm) af[fm] = *(const bf16x8*)(arp + fm * 512);
    #pragma unroll
    for (int fn = 0; fn < 4; ++fn) bfr[fn] = *(const bf16x8*)(brp + fn * 512);
    #pragma unroll
    for (int fm = 0; fm < 4; ++fm)
      #pragma unroll
      for (int fn = 0; fn < 4; ++fn)
        acc[fm][fn] = __builtin_amdgcn_mfma_f32_16x16x32_bf16(af[fm], bfr[fn], acc[fm][fn], 0, 0, 0);
    __syncthreads();
  }
  // epilogue: + b1, silu, bf16 store to h
  #pragma unroll
  for (int fn = 0; fn < 4; ++fn) {
    const int gcol = nt * 128 + wn * 64 + fn * 16 + lr;
    const float b1v = b1[e * IDIM + gcol];
    #pragma unroll
    for (int fm = 0; fm < 4; ++fm)
      #pragma unroll
      for (int rr = 0; rr < 4; ++rr) {
        const int grow = mt * 128 + wm * 64 + fm * 16 + (l >> 4) * 4 + rr;
        const float v = acc[fm][fn][rr] + b1v;
        const float sv = v / (1.f + expf(-v));
        h[(size_t)grow * IDIM + gcol] = f2b(sv);
      }
  }
}

// ---------------- grouped GEMM2: out[tok] += w * (h @ W2T^T + b2) ----------------
__global__ __launch_bounds__(256, 2) void gemm2_k(
    const unsigned short* __restrict__ h, const unsigned short* __restrict__ w2t,
    const float* __restrict__ b2, const int* __restrict__ meta,
    const int* __restrict__ ltok, const float* __restrict__ lw,
    float* __restrict__ out)
{
  const int mt = blockIdx.x, nt = blockIdx.y;
  if (mt * 128 >= meta[24]) return;
  int e = 0;
  #pragma unroll
  for (int i = 1; i < 8; ++i) if (meta[16 + i] <= mt * 128) e = i;

  __shared__ unsigned short As[128 * 32];
  __shared__ unsigned short Bs[128 * 32];
  const int t = threadIdx.x;
  const int w = t >> 6, l = t & 63;
  const int wm = w & 1, wn = w >> 1;
  const int r0 = t >> 2, c8 = (t & 3) * 8;

  const unsigned short* a0 = h + (size_t)(mt * 128 + r0) * IDIM + c8;
  const unsigned short* a1 = a0 + (size_t)64 * IDIM;
  const unsigned short* bp0 = w2t + ((size_t)e * HDIM + nt * 128 + r0) * IDIM + c8;
  const unsigned short* bp1 = bp0 + (size_t)64 * IDIM;

  unsigned short* sA0 = As + w * 512;
  unsigned short* sA1 = As + 2048 + w * 512;
  unsigned short* sB0 = Bs + w * 512;
  unsigned short* sB1 = Bs + 2048 + w * 512;

  const int lr = l & 15, lc = (l >> 4) * 8;
  const unsigned short* arp = As + (wm * 64 + lr) * 32 + lc;
  const unsigned short* brp = Bs + (wn * 64 + lr) * 32 + lc;

  f32x4 acc[4][4] = {};
  for (int ks = 0; ks < IDIM; ks += 32) {
    gld16(a0 + ks, sA0);
    gld16(a1 + ks, sA1);
    gld16(bp0 + ks, sB0);
    gld16(bp1 + ks, sB1);
    __syncthreads();
    bf16x8 af[4], bfr[4];
    #pragma unroll
    for (int fm = 0; fm < 4; ++fm) af[fm] = *(const bf16x8*)(arp + fm * 512);
    #pragma unroll
    for (int fn = 0; fn < 4; ++fn) bfr[fn] = *(const bf16x8*)(brp + fn * 512);
    #pragma unroll
    for (int fm = 0; fm < 4; ++fm)
      #pragma unroll
      for (int fn = 0; fn < 4; ++fn)
        acc[fm][fn] = __builtin_amdgcn_mfma_f32_16x16x32_bf16(af[fm], bfr[fn], acc[fm][fn], 0, 0, 0);
    __syncthreads();
  }
  // epilogue: weighted atomic scatter-add (exactly 2 adds per out element)
  float b2v[4];
  #pragma unroll
  for (int fn = 0; fn < 4; ++fn) b2v[fn] = b2[e * HDIM + nt * 128 + wn * 64 + fn * 16 + lr];
  #pragma unroll
  for (int fm = 0; fm < 4; ++fm)
    #pragma unroll
    for (int rr = 0; rr < 4; ++rr) {
      const int grow = mt * 128 + wm * 64 + fm * 16 + (l >> 4) * 4 + rr;
      const int tok = ltok[grow];
      if (tok >= 0) {
        const float wgt = lw[grow];
        #pragma unroll
        for (int fn = 0; fn < 4; ++fn) {
          const int gcol = nt * 128 + wn * 64 + fn * 16 + lr;
          atomicAdd(out + (size_t)tok * HDIM + gcol, wgt * (acc[fm][fn][rr] + b2v[fn]));
        }
      }
    }
}

__global__ void sentinel_k(float* out) { out[0] = 1.0e6f; }

// ---------------- launcher ----------------
extern "C" void kernel_launch(void* const* d_in, const int* in_sizes, int n_in,
                              void* d_out, int out_size, void* d_ws, size_t ws_size,
                              hipStream_t stream)
{
  (void)in_sizes; (void)n_in;
  const float* x  = (const float*)d_in[0];
  const float* wr = (const float*)d_in[1];
  const float* w1 = (const float*)d_in[2];
  const float* b1 = (const float*)d_in[3];
  const float* w2 = (const float*)d_in[4];
  const float* b2 = (const float*)d_in[5];
  float* out = (float*)d_out;
  char* ws = (char*)d_ws;

  if (ws_size < WS_NEED) { sentinel_k<<<1, 1, 0, stream>>>(out); return; }

  unsigned short* xb  = (unsigned short*)(ws);
  unsigned short* w1t = (unsigned short*)(ws + 16777216);
  unsigned short* w2t = (unsigned short*)(ws + 83886080);
  unsigned short* h   = (unsigned short*)(ws + 150994944);
  int*   t2e  = (int*)(ws + 293601280);
  float* t2w  = (float*)(ws + 293666816);
  int*   ltok = (int*)(ws + 293732352);
  float* lw   = (float*)(ws + 293801984);
  int*   meta = (int*)(ws + 293871616);

  hipMemsetAsync(meta, 0, 128, stream);
  hipMemsetAsync(d_out, 0, (size_t)out_size * sizeof(float), stream);

  router_k<<<TTOK / 4, 256, 0, stream>>>(x, wr, xb, t2e, t2w, meta);
  packT_k<<<NEXP * (HDIM / 32) * (IDIM / 256), 256, 0, stream>>>(w1, w1t, HDIM, IDIM);
  packT_k<<<NEXP * (IDIM / 32) * (HDIM / 256), 256, 0, stream>>>(w2, w2t, IDIM, HDIM);
  offsets_k<<<1, 64, 0, stream>>>(meta);
  initlist_k<<<PMAX / 256, 256, 0, stream>>>(ltok, lw);
  fill_k<<<TTOK / 256, 256, 0, stream>>>(t2e, t2w, meta, ltok, lw);

  dim3 g1(MT_MAX, IDIM / 128);
  gemm1_k<<<g1, 256, 0, stream>>>(xb, w1t, b1, meta, ltok, h);
  dim3 g2(MT_MAX, HDIM / 128);
  gemm2_k<<<g2, 256, 0, stream>>>(h, w2t, b2, meta, ltok, lw, out);
}

// Round 2
// 826.525 us; speedup vs baseline: 1.1923x; 1.1923x over previous
//
#include <hip/hip_runtime.h>
#include <cstdint>
#include <cstddef>

// ---------------- problem constants ----------------
#define TTOK 8192          // B*S tokens
#define HDIM 1024
#define IDIM 4096
#define NEXP 8
#define PMAX 17408         // 16384 + 8*128 (segment padding to 128)
#define MT_MAX 136         // PMAX/128 tiles max
#define WS_NEED 293937280ULL

typedef __attribute__((ext_vector_type(8))) short bf16x8;
typedef __attribute__((ext_vector_type(4))) float f32x4;

#define AS3 __attribute__((address_space(3)))
#define AS1 __attribute__((address_space(1)))

__device__ __forceinline__ void gld16(const void* g, void* s) {
  // async global->LDS, 16B/lane; LDS dest is wave-uniform base (+lane*16 in HW)
  __builtin_amdgcn_global_load_lds((const AS1 void*)g, (AS3 void*)s, 16, 0, 0);
}

__device__ __forceinline__ unsigned short f2b(float f) {
  unsigned u = __builtin_bit_cast(unsigned, f);
  unsigned r = ((u >> 16) & 1u) + 0x7FFFu;   // RNE
  return (unsigned short)((u + r) >> 16);
}

// meta layout (ints): [0..7] counts, [8..15] slots, [16..24] offs, meta[24]=padded total
// ---------------- router: logits, top2, x->bf16 ----------------
__global__ __launch_bounds__(256, 2) void router_k(
    const float* __restrict__ x, const float* __restrict__ wr,
    unsigned short* __restrict__ xb, int* __restrict__ t2e,
    float* __restrict__ t2w, int* __restrict__ meta)
{
  const int t = blockIdx.x * 4 + (threadIdx.x >> 6);
  const int l = threadIdx.x & 63;
  const float* xr = x + (size_t)t * HDIM;
  float acc[8] = {0.f,0.f,0.f,0.f,0.f,0.f,0.f,0.f};
  #pragma unroll
  for (int j = 0; j < 4; ++j) {
    const int base = j * 256 + l * 4;
    const float4 xv = *(const float4*)(xr + base);
    const float xa[4] = {xv.x, xv.y, xv.z, xv.w};
    ushort4 ub;
    ub.x = f2b(xa[0]); ub.y = f2b(xa[1]); ub.z = f2b(xa[2]); ub.w = f2b(xa[3]);
    *(ushort4*)(xb + (size_t)t * HDIM + base) = ub;
    #pragma unroll
    for (int ii = 0; ii < 4; ++ii) {
      const float4 w0 = *(const float4*)(wr + (size_t)(base + ii) * 8);
      const float4 w1 = *(const float4*)(wr + (size_t)(base + ii) * 8 + 4);
      acc[0] += xa[ii] * w0.x; acc[1] += xa[ii] * w0.y;
      acc[2] += xa[ii] * w0.z; acc[3] += xa[ii] * w0.w;
      acc[4] += xa[ii] * w1.x; acc[5] += xa[ii] * w1.y;
      acc[6] += xa[ii] * w1.z; acc[7] += xa[ii] * w1.w;
    }
  }
  #pragma unroll
  for (int e = 0; e < 8; ++e) {
    float v = acc[e];
    #pragma unroll
    for (int off = 32; off > 0; off >>= 1) v += __shfl_xor(v, off);
    acc[e] = v;
  }
  if (l == 0) {
    float l0 = -1e30f; int i0 = 0;
    #pragma unroll
    for (int e = 0; e < 8; ++e) if (acc[e] > l0) { l0 = acc[e]; i0 = e; }
    float l1 = -1e30f; int i1 = (i0 == 0) ? 1 : 0;
    #pragma unroll
    for (int e = 0; e < 8; ++e) if (e != i0 && acc[e] > l1) { l1 = acc[e]; i1 = e; }
    // renormalized top2 softmax == sigmoid of gap
    const float w0 = 1.f / (1.f + expf(l1 - l0));
    t2e[t * 2] = i0; t2e[t * 2 + 1] = i1;
    t2w[t * 2] = w0; t2w[t * 2 + 1] = 1.f - w0;
    atomicAdd(&meta[i0], 1); atomicAdd(&meta[i1], 1);
  }
}

// ---------------- offsets (1 thread) ----------------
__global__ void offsets_k(int* meta) {
  if (threadIdx.x == 0 && blockIdx.x == 0) {
    int off = 0;
    #pragma unroll
    for (int e = 0; e < 8; ++e) { meta[16 + e] = off; off += (meta[e] + 127) & ~127; }
    meta[24] = off;
  }
}

__global__ void initlist_k(int* __restrict__ ltok) {
  const int i = blockIdx.x * 256 + threadIdx.x;
  ltok[i] = -1;
}

__global__ void fill_k(const int* __restrict__ t2e, int* __restrict__ meta,
                       int* __restrict__ ltok, int* __restrict__ t2p)
{
  const int t = blockIdx.x * 256 + threadIdx.x;
  #pragma unroll
  for (int k = 0; k < 2; ++k) {
    const int e = t2e[t * 2 + k];
    const int p = atomicAdd(&meta[8 + e], 1);
    const int pos = meta[16 + e] + p;
    ltok[pos] = t;
    t2p[t * 2 + k] = pos;
  }
}

// ---------------- transpose-pack W[e][K][N] fp32 -> WT[e][N][K] bf16 ----------------
__global__ __launch_bounds__(256, 2) void packT_k(const float* __restrict__ src,
                                                  unsigned short* __restrict__ dst,
                                                  int K, int N)
{
  const int tiles_n = N >> 8, tiles_k = K >> 5;
  const int bid = blockIdx.x;
  const int e = bid / (tiles_k * tiles_n);
  const int rem = bid % (tiles_k * tiles_n);
  const int kt = rem / tiles_n, it = rem % tiles_n;
  const float* S = src + (size_t)e * K * N + (size_t)kt * 32 * N + (size_t)it * 256;
  unsigned short* D = dst + (size_t)e * N * K + (size_t)it * 256 * K + (size_t)kt * 32;
  __shared__ uint32_t lds[256 * 17];
  const int t = threadIdx.x;
  #pragma unroll
  for (int q = 0; q < 4; ++q) {
    const int task = q * 256 + t;
    const int i4 = task & 63, kp = task >> 6;
    const float* p0 = S + (size_t)(2 * kp) * N + i4 * 4;
    const float4 r0 = *(const float4*)p0;
    const float4 r1 = *(const float4*)(p0 + N);
    const float a0[4] = {r0.x, r0.y, r0.z, r0.w};
    const float a1[4] = {r1.x, r1.y, r1.z, r1.w};
    #pragma unroll
    for (int j = 0; j < 4; ++j)
      lds[(i4 * 4 + j) * 17 + kp] = (uint32_t)f2b(a0[j]) | ((uint32_t)f2b(a1[j]) << 16);
  }
  __syncthreads();
  #pragma unroll
  for (int r = 0; r < 4; ++r) {
    const int idx = r * 256 + t;
    const int il = idx >> 2, q4 = idx & 3;
    uint4 o;
    o.x = lds[il * 17 + q4 * 4 + 0];
    o.y = lds[il * 17 + q4 * 4 + 1];
    o.z = lds[il * 17 + q4 * 4 + 2];
    o.w = lds[il * 17 + q4 * 4 + 3];
    *(uint4*)(D + (size_t)il * K + q4 * 8) = o;
  }
}

// ---------------- grouped GEMM1: h = silu(Xg @ W1T^T + b1), bf16 out ----------------
// 128x128 tile, BK=64 (128B rows). LDS read-conflict-free via XOR swizzle:
// LDS[row][g_phys] holds data[row][g_phys ^ (row&7)], achieved with linear
// gld16 dest + inverse-swizzled per-lane SOURCE; reads XOR the granule back.
__global__ __launch_bounds__(256, 2) void gemm1_k(
    const unsigned short* __restrict__ xb, const unsigned short* __restrict__ w1t,
    const float* __restrict__ b1, const int* __restrict__ meta,
    const int* __restrict__ ltok, unsigned short* __restrict__ h)
{
  const int mt = blockIdx.x, nt = blockIdx.y;
  if (mt * 128 >= meta[24]) return;
  int e = 0;
  #pragma unroll
  for (int i = 1; i < 8; ++i) if (meta[16 + i] <= mt * 128) e = i;

  __shared__ unsigned short As[128 * 64];
  __shared__ unsigned short Bs[128 * 64];
  const int t = threadIdx.x;
  const int w = t >> 6, l = t & 63;
  const int wm = w & 1, wn = w >> 1;
  const int rl = l >> 3;             // row within 8-row chunk
  const int gsrc = (l & 7) ^ rl;     // inverse-swizzled source granule

  const unsigned short* sa[4]; const unsigned short* sb[4];
  unsigned short* da[4]; unsigned short* db[4];
  #pragma unroll
  for (int c = 0; c < 4; ++c) {
    const int chunk = w * 4 + c;
    const int row = chunk * 8 + rl;
    int tok = ltok[mt * 128 + row]; if (tok < 0) tok = 0;
    sa[c] = xb + (size_t)tok * HDIM + gsrc * 8;
    sb[c] = w1t + ((size_t)e * IDIM + nt * 128 + row) * HDIM + gsrc * 8;
    da[c] = As + chunk * 512;
    db[c] = Bs + chunk * 512;
  }

  const int lr = l & 15, lg = l >> 4;
  f32x4 acc[4][4] = {};
  for (int ks = 0; ks < HDIM; ks += 64) {
    #pragma unroll
    for (int c = 0; c < 4; ++c) { gld16(sa[c] + ks, da[c]); gld16(sb[c] + ks, db[c]); }
    __syncthreads();
    bf16x8 af[2][4], bfr[2][4];
    #pragma unroll
    for (int s = 0; s < 2; ++s) {
      #pragma unroll
      for (int fm = 0; fm < 4; ++fm) {
        const int row = wm * 64 + fm * 16 + lr;
        af[s][fm] = *(const bf16x8*)(As + row * 64 + (((s * 4 + lg) ^ (row & 7)) * 8));
      }
      #pragma unroll
      for (int fn = 0; fn < 4; ++fn) {
        const int row = wn * 64 + fn * 16 + lr;
        bfr[s][fn] = *(const bf16x8*)(Bs + row * 64 + (((s * 4 + lg) ^ (row & 7)) * 8));
      }
    }
    #pragma unroll
    for (int s = 0; s < 2; ++s)
      #pragma unroll
      for (int fm = 0; fm < 4; ++fm)
        #pragma unroll
        for (int fn = 0; fn < 4; ++fn)
          acc[fm][fn] = __builtin_amdgcn_mfma_f32_16x16x32_bf16(af[s][fm], bfr[s][fn], acc[fm][fn], 0, 0, 0);
    __syncthreads();
  }
  // epilogue: + b1, silu, bf16 store to h
  #pragma unroll
  for (int fn = 0; fn < 4; ++fn) {
    const int gcol = nt * 128 + wn * 64 + fn * 16 + lr;
    const float b1v = b1[e * IDIM + gcol];
    #pragma unroll
    for (int fm = 0; fm < 4; ++fm)
      #pragma unroll
      for (int rr = 0; rr < 4; ++rr) {
        const int grow = mt * 128 + wm * 64 + fm * 16 + (l >> 4) * 4 + rr;
        const float v = acc[fm][fn][rr] + b1v;
        const float sv = v / (1.f + __expf(-v));
        h[(size_t)grow * IDIM + gcol] = f2b(sv);
      }
  }
}

// ---------------- grouped GEMM2: y = h @ W2T^T (plain fp32 store) ----------------
__global__ __launch_bounds__(256, 2) void gemm2_k(
    const unsigned short* __restrict__ h, const unsigned short* __restrict__ w2t,
    const int* __restrict__ meta, float* __restrict__ y)
{
  const int mt = blockIdx.x, nt = blockIdx.y;
  if (mt * 128 >= meta[24]) return;
  int e = 0;
  #pragma unroll
  for (int i = 1; i < 8; ++i) if (meta[16 + i] <= mt * 128) e = i;

  __shared__ unsigned short As[128 * 64];
  __shared__ unsigned short Bs[128 * 64];
  const int t = threadIdx.x;
  const int w = t >> 6, l = t & 63;
  const int wm = w & 1, wn = w >> 1;
  const int rl = l >> 3;
  const int gsrc = (l & 7) ^ rl;

  const unsigned short* sa[4]; const unsigned short* sb[4];
  unsigned short* da[4]; unsigned short* db[4];
  #pragma unroll
  for (int c = 0; c < 4; ++c) {
    const int chunk = w * 4 + c;
    const int row = chunk * 8 + rl;
    sa[c] = h + (size_t)(mt * 128 + row) * IDIM + gsrc * 8;
    sb[c] = w2t + ((size_t)e * HDIM + nt * 128 + row) * IDIM + gsrc * 8;
    da[c] = As + chunk * 512;
    db[c] = Bs + chunk * 512;
  }

  const int lr = l & 15, lg = l >> 4;
  f32x4 acc[4][4] = {};
  for (int ks = 0; ks < IDIM; ks += 64) {
    #pragma unroll
    for (int c = 0; c < 4; ++c) { gld16(sa[c] + ks, da[c]); gld16(sb[c] + ks, db[c]); }
    __syncthreads();
    bf16x8 af[2][4], bfr[2][4];
    #pragma unroll
    for (int s = 0; s < 2; ++s) {
      #pragma unroll
      for (int fm = 0; fm < 4; ++fm) {
        const int row = wm * 64 + fm * 16 + lr;
        af[s][fm] = *(const bf16x8*)(As + row * 64 + (((s * 4 + lg) ^ (row & 7)) * 8));
      }
      #pragma unroll
      for (int fn = 0; fn < 4; ++fn) {
        const int row = wn * 64 + fn * 16 + lr;
        bfr[s][fn] = *(const bf16x8*)(Bs + row * 64 + (((s * 4 + lg) ^ (row & 7)) * 8));
      }
    }
    #pragma unroll
    for (int s = 0; s < 2; ++s)
      #pragma unroll
      for (int fm = 0; fm < 4; ++fm)
        #pragma unroll
        for (int fn = 0; fn < 4; ++fn)
          acc[fm][fn] = __builtin_amdgcn_mfma_f32_16x16x32_bf16(af[s][fm], bfr[s][fn], acc[fm][fn], 0, 0, 0);
    __syncthreads();
  }
  // epilogue: plain fp32 stores to y (combine kernel applies weights + b2)
  #pragma unroll
  for (int fm = 0; fm < 4; ++fm)
    #pragma unroll
    for (int rr = 0; rr < 4; ++rr) {
      const int grow = mt * 128 + wm * 64 + fm * 16 + (l >> 4) * 4 + rr;
      #pragma unroll
      for (int fn = 0; fn < 4; ++fn) {
        const int gcol = nt * 128 + wn * 64 + fn * 16 + lr;
        y[(size_t)grow * HDIM + gcol] = acc[fm][fn][rr];
      }
    }
}

// ---------------- combine: out[t] = w0*(y[p0]+b2[e0]) + w1*(y[p1]+b2[e1]) ----------------
__global__ __launch_bounds__(256, 4) void combine_k(
    const float* __restrict__ y, const float* __restrict__ b2,
    const int* __restrict__ t2e, const float* __restrict__ t2w,
    const int* __restrict__ t2p, float* __restrict__ out)
{
  const int t = blockIdx.x * 4 + (threadIdx.x >> 6);
  const int l = threadIdx.x & 63;
  const int e0 = t2e[t * 2], e1 = t2e[t * 2 + 1];
  const float w0 = t2w[t * 2], w1v = t2w[t * 2 + 1];
  const int p0 = t2p[t * 2], p1 = t2p[t * 2 + 1];
  const float* y0 = y + (size_t)p0 * HDIM;
  const float* y1 = y + (size_t)p1 * HDIM;
  const float* bb0 = b2 + e0 * HDIM;
  const float* bb1 = b2 + e1 * HDIM;
  float* o = out + (size_t)t * HDIM;
  #pragma unroll
  for (int j = 0; j < 4; ++j) {
    const int c = j * 256 + l * 4;
    const float4 a = *(const float4*)(y0 + c);
    const float4 b = *(const float4*)(y1 + c);
    const float4 c0 = *(const float4*)(bb0 + c);
    const float4 c1 = *(const float4*)(bb1 + c);
    float4 r;
    r.x = w0 * (a.x + c0.x) + w1v * (b.x + c1.x);
    r.y = w0 * (a.y + c0.y) + w1v * (b.y + c1.y);
    r.z = w0 * (a.z + c0.z) + w1v * (b.z + c1.z);
    r.w = w0 * (a.w + c0.w) + w1v * (b.w + c1.w);
    *(float4*)(o + c) = r;
  }
}

__global__ void sentinel_k(float* out) { out[0] = 1.0e6f; }

// ---------------- launcher ----------------
extern "C" void kernel_launch(void* const* d_in, const int* in_sizes, int n_in,
                              void* d_out, int out_size, void* d_ws, size_t ws_size,
                              hipStream_t stream)
{
  (void)in_sizes; (void)n_in; (void)out_size;
  const float* x  = (const float*)d_in[0];
  const float* wr = (const float*)d_in[1];
  const float* w1 = (const float*)d_in[2];
  const float* b1 = (const float*)d_in[3];
  const float* w2 = (const float*)d_in[4];
  const float* b2 = (const float*)d_in[5];
  float* out = (float*)d_out;
  char* ws = (char*)d_ws;

  if (ws_size < WS_NEED) { sentinel_k<<<1, 1, 0, stream>>>(out); return; }

  unsigned short* xb  = (unsigned short*)(ws);
  unsigned short* w1t = (unsigned short*)(ws + 16777216);
  unsigned short* w2t = (unsigned short*)(ws + 83886080);
  unsigned short* h   = (unsigned short*)(ws + 150994944);
  int*   t2e  = (int*)(ws + 293601280);
  float* t2w  = (float*)(ws + 293666816);
  int*   ltok = (int*)(ws + 293732352);
  int*   t2p  = (int*)(ws + 293801984);
  int*   meta = (int*)(ws + 293871616);
  // y aliases xb+w1t (both dead after gemm1): PMAX*HDIM*4 = 71.3MB < 83.9MB
  float* y    = (float*)(ws);

  hipMemsetAsync(meta, 0, 128, stream);

  router_k<<<TTOK / 4, 256, 0, stream>>>(x, wr, xb, t2e, t2w, meta);
  packT_k<<<NEXP * (HDIM / 32) * (IDIM / 256), 256, 0, stream>>>(w1, w1t, HDIM, IDIM);
  packT_k<<<NEXP * (IDIM / 32) * (HDIM / 256), 256, 0, stream>>>(w2, w2t, IDIM, HDIM);
  offsets_k<<<1, 64, 0, stream>>>(meta);
  initlist_k<<<PMAX / 256, 256, 0, stream>>>(ltok);
  fill_k<<<TTOK / 256, 256, 0, stream>>>(t2e, meta, ltok, t2p);

  dim3 g1(MT_MAX, IDIM / 128);
  gemm1_k<<<g1, 256, 0, stream>>>(xb, w1t, b1, meta, ltok, h);
  dim3 g2(MT_MAX, HDIM / 128);
  gemm2_k<<<g2, 256, 0, stream>>>(h, w2t, meta, y);
  combine_k<<<TTOK / 4, 256, 0, stream>>>(y, b2, t2e, t2w, t2p, out);
}

// Round 3
// 811.744 us; speedup vs baseline: 1.2140x; 1.0182x over previous
//
#include <hip/hip_runtime.h>
#include <cstdint>
#include <cstddef>

// ---------------- problem constants ----------------
#define TTOK 8192          // B*S tokens
#define HDIM 1024
#define IDIM 4096
#define NEXP 8
#define PMAX 17408         // 16384 + 8*128 (segment padding to 128)
#define MT_MAX 136         // PMAX/128 tiles max
#define WS_NEED 293937280ULL

typedef __attribute__((ext_vector_type(8))) short bf16x8;
typedef __attribute__((ext_vector_type(4))) float f32x4;

#define AS3 __attribute__((address_space(3)))
#define AS1 __attribute__((address_space(1)))

__device__ __forceinline__ void gld16(const void* g, void* s) {
  // async global->LDS, 16B/lane; LDS dest is wave-uniform base (+lane*16 in HW)
  __builtin_amdgcn_global_load_lds((const AS1 void*)g, (AS3 void*)s, 16, 0, 0);
}

__device__ __forceinline__ unsigned short f2b(float f) {
  unsigned u = __builtin_bit_cast(unsigned, f);
  unsigned r = ((u >> 16) & 1u) + 0x7FFFu;   // RNE
  return (unsigned short)((u + r) >> 16);
}

// meta layout (ints): [0..7] counts, [8..15] slots, [16..24] offs, meta[24]=padded total
// ---------------- router: logits, top2, x->bf16 ----------------
__global__ __launch_bounds__(256, 2) void router_k(
    const float* __restrict__ x, const float* __restrict__ wr,
    unsigned short* __restrict__ xb, int* __restrict__ t2e,
    float* __restrict__ t2w, int* __restrict__ meta)
{
  const int t = blockIdx.x * 4 + (threadIdx.x >> 6);
  const int l = threadIdx.x & 63;
  const float* xr = x + (size_t)t * HDIM;
  float acc[8] = {0.f,0.f,0.f,0.f,0.f,0.f,0.f,0.f};
  #pragma unroll
  for (int j = 0; j < 4; ++j) {
    const int base = j * 256 + l * 4;
    const float4 xv = *(const float4*)(xr + base);
    const float xa[4] = {xv.x, xv.y, xv.z, xv.w};
    ushort4 ub;
    ub.x = f2b(xa[0]); ub.y = f2b(xa[1]); ub.z = f2b(xa[2]); ub.w = f2b(xa[3]);
    *(ushort4*)(xb + (size_t)t * HDIM + base) = ub;
    #pragma unroll
    for (int ii = 0; ii < 4; ++ii) {
      const float4 w0 = *(const float4*)(wr + (size_t)(base + ii) * 8);
      const float4 w1 = *(const float4*)(wr + (size_t)(base + ii) * 8 + 4);
      acc[0] += xa[ii] * w0.x; acc[1] += xa[ii] * w0.y;
      acc[2] += xa[ii] * w0.z; acc[3] += xa[ii] * w0.w;
      acc[4] += xa[ii] * w1.x; acc[5] += xa[ii] * w1.y;
      acc[6] += xa[ii] * w1.z; acc[7] += xa[ii] * w1.w;
    }
  }
  #pragma unroll
  for (int e = 0; e < 8; ++e) {
    float v = acc[e];
    #pragma unroll
    for (int off = 32; off > 0; off >>= 1) v += __shfl_xor(v, off);
    acc[e] = v;
  }
  if (l == 0) {
    float l0 = -1e30f; int i0 = 0;
    #pragma unroll
    for (int e = 0; e < 8; ++e) if (acc[e] > l0) { l0 = acc[e]; i0 = e; }
    float l1 = -1e30f; int i1 = (i0 == 0) ? 1 : 0;
    #pragma unroll
    for (int e = 0; e < 8; ++e) if (e != i0 && acc[e] > l1) { l1 = acc[e]; i1 = e; }
    // renormalized top2 softmax == sigmoid of gap
    const float w0 = 1.f / (1.f + expf(l1 - l0));
    t2e[t * 2] = i0; t2e[t * 2 + 1] = i1;
    t2w[t * 2] = w0; t2w[t * 2 + 1] = 1.f - w0;
    atomicAdd(&meta[i0], 1); atomicAdd(&meta[i1], 1);
  }
}

// ---------------- offsets (1 thread) ----------------
__global__ void offsets_k(int* meta) {
  if (threadIdx.x == 0 && blockIdx.x == 0) {
    int off = 0;
    #pragma unroll
    for (int e = 0; e < 8; ++e) { meta[16 + e] = off; off += (meta[e] + 127) & ~127; }
    meta[24] = off;
  }
}

__global__ void initlist_k(int* __restrict__ ltok) {
  const int i = blockIdx.x * 256 + threadIdx.x;
  ltok[i] = -1;
}

__global__ void fill_k(const int* __restrict__ t2e, int* __restrict__ meta,
                       int* __restrict__ ltok, int* __restrict__ t2p)
{
  const int t = blockIdx.x * 256 + threadIdx.x;
  #pragma unroll
  for (int k = 0; k < 2; ++k) {
    const int e = t2e[t * 2 + k];
    const int p = atomicAdd(&meta[8 + e], 1);
    const int pos = meta[16 + e] + p;
    ltok[pos] = t;
    t2p[t * 2 + k] = pos;
  }
}

// ---------------- transpose-pack W[e][K][N] fp32 -> WT[e][N][K] bf16 ----------------
__global__ __launch_bounds__(256, 2) void packT_k(const float* __restrict__ src,
                                                  unsigned short* __restrict__ dst,
                                                  int K, int N)
{
  const int tiles_n = N >> 8, tiles_k = K >> 5;
  const int bid = blockIdx.x;
  const int e = bid / (tiles_k * tiles_n);
  const int rem = bid % (tiles_k * tiles_n);
  const int kt = rem / tiles_n, it = rem % tiles_n;
  const float* S = src + (size_t)e * K * N + (size_t)kt * 32 * N + (size_t)it * 256;
  unsigned short* D = dst + (size_t)e * N * K + (size_t)it * 256 * K + (size_t)kt * 32;
  __shared__ uint32_t lds[256 * 17];
  const int t = threadIdx.x;
  #pragma unroll
  for (int q = 0; q < 4; ++q) {
    const int task = q * 256 + t;
    const int i4 = task & 63, kp = task >> 6;
    const float* p0 = S + (size_t)(2 * kp) * N + i4 * 4;
    const float4 r0 = *(const float4*)p0;
    const float4 r1 = *(const float4*)(p0 + N);
    const float a0[4] = {r0.x, r0.y, r0.z, r0.w};
    const float a1[4] = {r1.x, r1.y, r1.z, r1.w};
    #pragma unroll
    for (int j = 0; j < 4; ++j)
      lds[(i4 * 4 + j) * 17 + kp] = (uint32_t)f2b(a0[j]) | ((uint32_t)f2b(a1[j]) << 16);
  }
  __syncthreads();
  #pragma unroll
  for (int r = 0; r < 4; ++r) {
    const int idx = r * 256 + t;
    const int il = idx >> 2, q4 = idx & 3;
    uint4 o;
    o.x = lds[il * 17 + q4 * 4 + 0];
    o.y = lds[il * 17 + q4 * 4 + 1];
    o.z = lds[il * 17 + q4 * 4 + 2];
    o.w = lds[il * 17 + q4 * 4 + 3];
    *(uint4*)(D + (size_t)il * K + q4 * 8) = o;
  }
}

// ---------------- grouped GEMM1: h = silu(W1T-tile x Xg-tile + b1) ----------------
// Swapped operands: A-frags = W1T rows (i-dim), B-frags = gathered token rows.
// D rows (reg idx) run along i => epilogue packs 4 consecutive i into ushort4.
// 128x128 tile, BK=64, 2-phase double-buffered LDS (2 x (16+16) KB dynamic).
__global__ __launch_bounds__(256, 2) void gemm1_k(
    const unsigned short* __restrict__ xb, const unsigned short* __restrict__ w1t,
    const float* __restrict__ b1, const int* __restrict__ meta,
    const int* __restrict__ ltok, unsigned short* __restrict__ h)
{
  // XCD-aware swizzle: grid 136*32 = 4352 linear; each XCD gets contiguous mt-range
  const int wg = blockIdx.x;
  const int id = (wg & 7) * (4352 >> 3) + (wg >> 3);
  const int mt = id >> 5, nt = id & 31;
  if (mt * 128 >= meta[24]) return;
  int e = 0;
  #pragma unroll
  for (int i = 1; i < 8; ++i) if (meta[16 + i] <= mt * 128) e = i;

  extern __shared__ unsigned short lds[];
  unsigned short* As = lds;           // [2][128*64] W1T rows (i)
  unsigned short* Bs = lds + 16384;   // [2][128*64] token rows

  const int t = threadIdx.x;
  const int w = t >> 6, l = t & 63;
  const int wm = w & 1, wn = w >> 1;
  const int rl = l >> 3;              // row within 8-row chunk
  const int gsrc = (l & 7) ^ rl;      // inverse-swizzled source granule

  const unsigned short* sa[4]; const unsigned short* sb[4];
  int doff[4];
  #pragma unroll
  for (int c = 0; c < 4; ++c) {
    const int chunk = w * 4 + c;
    const int row = chunk * 8 + rl;
    sa[c] = w1t + ((size_t)e * IDIM + nt * 128 + row) * HDIM + gsrc * 8;
    int tok = ltok[mt * 128 + row]; if (tok < 0) tok = 0;
    sb[c] = xb + (size_t)tok * HDIM + gsrc * 8;
    doff[c] = chunk * 512;
  }

  const int lr = l & 15, lg = l >> 4;
  f32x4 acc[4][4] = {};

  // prologue: stage K-tile 0 into buf 0
  #pragma unroll
  for (int c = 0; c < 4; ++c) { gld16(sa[c], As + doff[c]); gld16(sb[c], Bs + doff[c]); }
  __syncthreads();

  int buf = 0;
  for (int kt = 0; kt < HDIM / 64; ++kt) {
    // stage next K-tile into other buffer FIRST (latency overlaps compute)
    if (kt + 1 < HDIM / 64) {
      const int ks = (kt + 1) * 64;
      const int nb = (buf ^ 1) * 8192;
      #pragma unroll
      for (int c = 0; c < 4; ++c) {
        gld16(sa[c] + ks, As + nb + doff[c]);
        gld16(sb[c] + ks, Bs + nb + doff[c]);
      }
    }
    const unsigned short* Ab = As + buf * 8192;
    const unsigned short* Bb = Bs + buf * 8192;
    bf16x8 af[2][4], bfv[2][4];
    #pragma unroll
    for (int s = 0; s < 2; ++s) {
      #pragma unroll
      for (int f = 0; f < 4; ++f) {
        const int rowA = wm * 64 + f * 16 + lr;
        af[s][f] = *(const bf16x8*)(Ab + rowA * 64 + (((s * 4 + lg) ^ (rowA & 7)) << 3));
        const int rowB = wn * 64 + f * 16 + lr;
        bfv[s][f] = *(const bf16x8*)(Bb + rowB * 64 + (((s * 4 + lg) ^ (rowB & 7)) << 3));
      }
    }
    #pragma unroll
    for (int s = 0; s < 2; ++s)
      #pragma unroll
      for (int fm = 0; fm < 4; ++fm)
        #pragma unroll
        for (int fn = 0; fn < 4; ++fn)
          acc[fm][fn] = __builtin_amdgcn_mfma_f32_16x16x32_bf16(af[s][fm], bfv[s][fn], acc[fm][fn], 0, 0, 0);
    __syncthreads();
    buf ^= 1;
  }

  // epilogue: +b1, silu, packed ushort4 stores (4 consecutive i per lane)
  #pragma unroll
  for (int fm = 0; fm < 4; ++fm) {
    const int gcb = nt * 128 + wm * 64 + fm * 16 + lg * 4;   // i base
    const float4 b1v = *(const float4*)(b1 + e * IDIM + gcb);
    #pragma unroll
    for (int fn = 0; fn < 4; ++fn) {
      const int grow = mt * 128 + wn * 64 + fn * 16 + lr;    // padded slot
      float v0 = acc[fm][fn][0] + b1v.x;
      float v1 = acc[fm][fn][1] + b1v.y;
      float v2 = acc[fm][fn][2] + b1v.z;
      float v3 = acc[fm][fn][3] + b1v.w;
      ushort4 st;
      st.x = f2b(v0 / (1.f + __expf(-v0)));
      st.y = f2b(v1 / (1.f + __expf(-v1)));
      st.z = f2b(v2 / (1.f + __expf(-v2)));
      st.w = f2b(v3 / (1.f + __expf(-v3)));
      *(ushort4*)(h + (size_t)grow * IDIM + gcb) = st;
    }
  }
}

// ---------------- grouped GEMM2: y = h @ W2T^T (coalesced float4 stores) ----------------
__global__ __launch_bounds__(256, 2) void gemm2_k(
    const unsigned short* __restrict__ h, const unsigned short* __restrict__ w2t,
    const int* __restrict__ meta, float* __restrict__ y)
{
  // grid 136*8 = 1088 linear; XCD swizzle -> contiguous mt per XCD (h-row L2 reuse)
  const int wg = blockIdx.x;
  const int id = (wg & 7) * (1088 >> 3) + (wg >> 3);
  const int mt = id >> 3, nt = id & 7;
  if (mt * 128 >= meta[24]) return;
  int e = 0;
  #pragma unroll
  for (int i = 1; i < 8; ++i) if (meta[16 + i] <= mt * 128) e = i;

  extern __shared__ unsigned short lds[];
  unsigned short* As = lds;           // [2][128*64] W2T rows (hcol)
  unsigned short* Bs = lds + 16384;   // [2][128*64] h rows

  const int t = threadIdx.x;
  const int w = t >> 6, l = t & 63;
  const int wm = w & 1, wn = w >> 1;
  const int rl = l >> 3;
  const int gsrc = (l & 7) ^ rl;

  const unsigned short* sa[4]; const unsigned short* sb[4];
  int doff[4];
  #pragma unroll
  for (int c = 0; c < 4; ++c) {
    const int chunk = w * 4 + c;
    const int row = chunk * 8 + rl;
    sa[c] = w2t + ((size_t)e * HDIM + nt * 128 + row) * IDIM + gsrc * 8;
    sb[c] = h + (size_t)(mt * 128 + row) * IDIM + gsrc * 8;
    doff[c] = chunk * 512;
  }

  const int lr = l & 15, lg = l >> 4;
  f32x4 acc[4][4] = {};

  #pragma unroll
  for (int c = 0; c < 4; ++c) { gld16(sa[c], As + doff[c]); gld16(sb[c], Bs + doff[c]); }
  __syncthreads();

  int buf = 0;
  for (int kt = 0; kt < IDIM / 64; ++kt) {
    if (kt + 1 < IDIM / 64) {
      const int ks = (kt + 1) * 64;
      const int nb = (buf ^ 1) * 8192;
      #pragma unroll
      for (int c = 0; c < 4; ++c) {
        gld16(sa[c] + ks, As + nb + doff[c]);
        gld16(sb[c] + ks, Bs + nb + doff[c]);
      }
    }
    const unsigned short* Ab = As + buf * 8192;
    const unsigned short* Bb = Bs + buf * 8192;
    bf16x8 af[2][4], bfv[2][4];
    #pragma unroll
    for (int s = 0; s < 2; ++s) {
      #pragma unroll
      for (int f = 0; f < 4; ++f) {
        const int rowA = wm * 64 + f * 16 + lr;
        af[s][f] = *(const bf16x8*)(Ab + rowA * 64 + (((s * 4 + lg) ^ (rowA & 7)) << 3));
        const int rowB = wn * 64 + f * 16 + lr;
        bfv[s][f] = *(const bf16x8*)(Bb + rowB * 64 + (((s * 4 + lg) ^ (rowB & 7)) << 3));
      }
    }
    #pragma unroll
    for (int s = 0; s < 2; ++s)
      #pragma unroll
      for (int fm = 0; fm < 4; ++fm)
        #pragma unroll
        for (int fn = 0; fn < 4; ++fn)
          acc[fm][fn] = __builtin_amdgcn_mfma_f32_16x16x32_bf16(af[s][fm], bfv[s][fn], acc[fm][fn], 0, 0, 0);
    __syncthreads();
    buf ^= 1;
  }

  // epilogue: coalesced float4 stores (4 consecutive hcol per lane)
  #pragma unroll
  for (int fm = 0; fm < 4; ++fm) {
    const int colb = nt * 128 + wm * 64 + fm * 16 + lg * 4;  // hcol base
    #pragma unroll
    for (int fn = 0; fn < 4; ++fn) {
      const int row = mt * 128 + wn * 64 + fn * 16 + lr;     // padded slot
      float4 st;
      st.x = acc[fm][fn][0]; st.y = acc[fm][fn][1];
      st.z = acc[fm][fn][2]; st.w = acc[fm][fn][3];
      *(float4*)(y + (size_t)row * HDIM + colb) = st;
    }
  }
}

// ---------------- combine: out[t] = w0*(y[p0]+b2[e0]) + w1*(y[p1]+b2[e1]) ----------------
__global__ __launch_bounds__(256, 4) void combine_k(
    const float* __restrict__ y, const float* __restrict__ b2,
    const int* __restrict__ t2e, const float* __restrict__ t2w,
    const int* __restrict__ t2p, float* __restrict__ out)
{
  const int t = blockIdx.x * 4 + (threadIdx.x >> 6);
  const int l = threadIdx.x & 63;
  const int e0 = t2e[t * 2], e1 = t2e[t * 2 + 1];
  const float w0 = t2w[t * 2], w1v = t2w[t * 2 + 1];
  const int p0 = t2p[t * 2], p1 = t2p[t * 2 + 1];
  const float* y0 = y + (size_t)p0 * HDIM;
  const float* y1 = y + (size_t)p1 * HDIM;
  const float* bb0 = b2 + e0 * HDIM;
  const float* bb1 = b2 + e1 * HDIM;
  float* o = out + (size_t)t * HDIM;
  #pragma unroll
  for (int j = 0; j < 4; ++j) {
    const int c = j * 256 + l * 4;
    const float4 a = *(const float4*)(y0 + c);
    const float4 b = *(const float4*)(y1 + c);
    const float4 c0 = *(const float4*)(bb0 + c);
    const float4 c1 = *(const float4*)(bb1 + c);
    float4 r;
    r.x = w0 * (a.x + c0.x) + w1v * (b.x + c1.x);
    r.y = w0 * (a.y + c0.y) + w1v * (b.y + c1.y);
    r.z = w0 * (a.z + c0.z) + w1v * (b.z + c1.z);
    r.w = w0 * (a.w + c0.w) + w1v * (b.w + c1.w);
    *(float4*)(o + c) = r;
  }
}

__global__ void sentinel_k(float* out) { out[0] = 1.0e6f; }

// ---------------- launcher ----------------
extern "C" void kernel_launch(void* const* d_in, const int* in_sizes, int n_in,
                              void* d_out, int out_size, void* d_ws, size_t ws_size,
                              hipStream_t stream)
{
  (void)in_sizes; (void)n_in; (void)out_size;
  const float* x  = (const float*)d_in[0];
  const float* wr = (const float*)d_in[1];
  const float* w1 = (const float*)d_in[2];
  const float* b1 = (const float*)d_in[3];
  const float* w2 = (const float*)d_in[4];
  const float* b2 = (const float*)d_in[5];
  float* out = (float*)d_out;
  char* ws = (char*)d_ws;

  if (ws_size < WS_NEED) { sentinel_k<<<1, 1, 0, stream>>>(out); return; }

  unsigned short* xb  = (unsigned short*)(ws);
  unsigned short* w1t = (unsigned short*)(ws + 16777216);
  unsigned short* w2t = (unsigned short*)(ws + 83886080);
  unsigned short* h   = (unsigned short*)(ws + 150994944);
  int*   t2e  = (int*)(ws + 293601280);
  float* t2w  = (float*)(ws + 293666816);
  int*   ltok = (int*)(ws + 293732352);
  int*   t2p  = (int*)(ws + 293801984);
  int*   meta = (int*)(ws + 293871616);
  // y aliases xb+w1t (both dead after gemm1): PMAX*HDIM*4 = 71.3MB < 83.9MB
  float* y    = (float*)(ws);

  hipMemsetAsync(meta, 0, 128, stream);

  router_k<<<TTOK / 4, 256, 0, stream>>>(x, wr, xb, t2e, t2w, meta);
  packT_k<<<NEXP * (HDIM / 32) * (IDIM / 256), 256, 0, stream>>>(w1, w1t, HDIM, IDIM);
  packT_k<<<NEXP * (IDIM / 32) * (HDIM / 256), 256, 0, stream>>>(w2, w2t, IDIM, HDIM);
  offsets_k<<<1, 64, 0, stream>>>(meta);
  initlist_k<<<PMAX / 256, 256, 0, stream>>>(ltok);
  fill_k<<<TTOK / 256, 256, 0, stream>>>(t2e, meta, ltok, t2p);

  gemm1_k<<<MT_MAX * (IDIM / 128), 256, 65536, stream>>>(xb, w1t, b1, meta, ltok, h);
  gemm2_k<<<MT_MAX * (HDIM / 128), 256, 65536, stream>>>(h, w2t, meta, y);
  combine_k<<<TTOK / 4, 256, 0, stream>>>(y, b2, t2e, t2w, t2p, out);
}

// Round 5
// 638.307 us; speedup vs baseline: 1.5439x; 1.2717x over previous
//
#include <hip/hip_runtime.h>
#include <cstdint>
#include <cstddef>

// ---------------- problem constants ----------------
#define TTOK 8192          // B*S tokens
#define HDIM 1024
#define IDIM 4096
#define NEXP 8
#define PMAX 18432         // 16384 + 8*256 (segment padding to 256)
#define MT_MAX 72          // PMAX/256 tiles max
#define WS_NEED 302260352ULL

typedef __attribute__((ext_vector_type(8))) short bf16x8;
typedef __attribute__((ext_vector_type(4))) float f32x4;

#define AS3 __attribute__((address_space(3)))
#define AS1 __attribute__((address_space(1)))

__device__ __forceinline__ void gld16(const void* g, void* s) {
  // async global->LDS, 16B/lane; LDS dest is wave-uniform base (+lane*16 in HW)
  __builtin_amdgcn_global_load_lds((const AS1 void*)g, (AS3 void*)s, 16, 0, 0);
}

__device__ __forceinline__ unsigned short f2b(float f) {
  unsigned u = __builtin_bit_cast(unsigned, f);
  unsigned r = ((u >> 16) & 1u) + 0x7FFFu;   // RNE
  return (unsigned short)((u + r) >> 16);
}

// meta layout (ints): [0..7] counts, [16..23] offs, meta[24]=padded total
// ---------------- router: logits, top2, x->bf16 (no atomics) ----------------
__global__ __launch_bounds__(256, 2) void router_k(
    const float* __restrict__ x, const float* __restrict__ wr,
    unsigned short* __restrict__ xb, int* __restrict__ t2e,
    float* __restrict__ t2w)
{
  const int t = blockIdx.x * 4 + (threadIdx.x >> 6);
  const int l = threadIdx.x & 63;
  const float* xr = x + (size_t)t * HDIM;
  float acc[8] = {0.f,0.f,0.f,0.f,0.f,0.f,0.f,0.f};
  #pragma unroll
  for (int j = 0; j < 4; ++j) {
    const int base = j * 256 + l * 4;
    const float4 xv = *(const float4*)(xr + base);
    const float xa[4] = {xv.x, xv.y, xv.z, xv.w};
    ushort4 ub;
    ub.x = f2b(xa[0]); ub.y = f2b(xa[1]); ub.z = f2b(xa[2]); ub.w = f2b(xa[3]);
    *(ushort4*)(xb + (size_t)t * HDIM + base) = ub;
    #pragma unroll
    for (int ii = 0; ii < 4; ++ii) {
      const float4 w0 = *(const float4*)(wr + (size_t)(base + ii) * 8);
      const float4 w1 = *(const float4*)(wr + (size_t)(base + ii) * 8 + 4);
      acc[0] += xa[ii] * w0.x; acc[1] += xa[ii] * w0.y;
      acc[2] += xa[ii] * w0.z; acc[3] += xa[ii] * w0.w;
      acc[4] += xa[ii] * w1.x; acc[5] += xa[ii] * w1.y;
      acc[6] += xa[ii] * w1.z; acc[7] += xa[ii] * w1.w;
    }
  }
  #pragma unroll
  for (int e = 0; e < 8; ++e) {
    float v = acc[e];
    #pragma unroll
    for (int off = 32; off > 0; off >>= 1) v += __shfl_xor(v, off);
    acc[e] = v;
  }
  if (l == 0) {
    float l0 = -1e30f; int i0 = 0;
    #pragma unroll
    for (int e = 0; e < 8; ++e) if (acc[e] > l0) { l0 = acc[e]; i0 = e; }
    float l1 = -1e30f; int i1 = (i0 == 0) ? 1 : 0;
    #pragma unroll
    for (int e = 0; e < 8; ++e) if (e != i0 && acc[e] > l1) { l1 = acc[e]; i1 = e; }
    // renormalized top2 softmax == sigmoid of gap
    const float w0 = 1.f / (1.f + expf(l1 - l0));
    t2e[t * 2] = i0; t2e[t * 2 + 1] = i1;
    t2w[t * 2] = w0; t2w[t * 2 + 1] = 1.f - w0;
  }
}

// ---------------- count: ballot histogram, offsets (1 block, no atomics) ----
__global__ void count_k(const int* __restrict__ t2e, int* __restrict__ meta) {
  const int t = threadIdx.x, w = t >> 6, l = t & 63;
  int cnt[8] = {0,0,0,0,0,0,0,0};
  for (int c = 0; c < 16; ++c) {               // 8 waves x 16 x 64 = 8192
    const int tok = (w * 16 + c) * 64 + l;
    const int e0 = t2e[2 * tok], e1 = t2e[2 * tok + 1];
    #pragma unroll
    for (int e = 0; e < 8; ++e)
      cnt[e] += __popcll(__ballot(e0 == e)) + __popcll(__ballot(e1 == e));
  }
  __shared__ int part[8][8];
  if (l == 0) {
    #pragma unroll
    for (int e = 0; e < 8; ++e) part[w][e] = cnt[e];
  }
  __syncthreads();
  if (t == 0) {
    int off = 0;
    #pragma unroll
    for (int e = 0; e < 8; ++e) {
      int s = 0;
      #pragma unroll
      for (int w2 = 0; w2 < 8; ++w2) s += part[w2][e];
      meta[e] = s; meta[16 + e] = off; off += (s + 255) & ~255;
    }
    meta[24] = off;
  }
}

// ---------------- scatter: deterministic per-expert prefix scan -------------
__global__ void scatter_k(const int* __restrict__ t2e, const int* __restrict__ meta,
                          int* __restrict__ ltok, int* __restrict__ t2p)
{
  const int e = blockIdx.x;
  const int t = threadIdx.x, w = t >> 6, l = t & 63;
  const int off = meta[16 + e];
  const int cnt = meta[e];
  __shared__ int wsum[4];
  __shared__ int base;
  if (t == 0) base = 0;
  __syncthreads();
  const unsigned long long lt = (1ULL << l) - 1ULL;
  for (int c = 0; c < TTOK / 256; ++c) {
    const int tok = c * 256 + t;
    const bool m0 = (t2e[2 * tok] == e);
    const bool m1 = (t2e[2 * tok + 1] == e);
    const unsigned long long b0 = __ballot(m0);
    const unsigned long long b1 = __ballot(m1);
    const int n0 = __popcll(b0), n1 = __popcll(b1);
    const int r0 = __popcll(b0 & lt);
    const int r1 = n0 + __popcll(b1 & lt);
    if (l == 0) wsum[w] = n0 + n1;
    __syncthreads();
    int wb = base;
    #pragma unroll
    for (int i = 0; i < 4; ++i) if (i < w) wb += wsum[i];
    const int tot = wsum[0] + wsum[1] + wsum[2] + wsum[3];
    __syncthreads();
    if (t == 0) base += tot;
    if (m0) { const int p = off + wb + r0; ltok[p] = tok; t2p[2 * tok] = p; }
    if (m1) { const int p = off + wb + r1; ltok[p] = tok; t2p[2 * tok + 1] = p; }
    __syncthreads();
  }
  const int padded = (cnt + 255) & ~255;
  for (int i = cnt + t; i < padded; i += 256) ltok[off + i] = -1;
}

// ---------------- transpose-pack W[e][K][N] fp32 -> WT[e][N][K] bf16 ----------------
__global__ __launch_bounds__(256, 2) void packT_k(const float* __restrict__ src,
                                                  unsigned short* __restrict__ dst,
                                                  int K, int N)
{
  const int tiles_n = N >> 8, tiles_k = K >> 5;
  const int bid = blockIdx.x;
  const int e = bid / (tiles_k * tiles_n);
  const int rem = bid % (tiles_k * tiles_n);
  const int kt = rem / tiles_n, it = rem % tiles_n;
  const float* S = src + (size_t)e * K * N + (size_t)kt * 32 * N + (size_t)it * 256;
  unsigned short* D = dst + (size_t)e * N * K + (size_t)it * 256 * K + (size_t)kt * 32;
  __shared__ uint32_t lds[256 * 17];
  const int t = threadIdx.x;
  #pragma unroll
  for (int q = 0; q < 4; ++q) {
    const int task = q * 256 + t;
    const int i4 = task & 63, kp = task >> 6;
    const float* p0 = S + (size_t)(2 * kp) * N + i4 * 4;
    const float4 r0 = *(const float4*)p0;
    const float4 r1 = *(const float4*)(p0 + N);
    const float a0[4] = {r0.x, r0.y, r0.z, r0.w};
    const float a1[4] = {r1.x, r1.y, r1.z, r1.w};
    #pragma unroll
    for (int j = 0; j < 4; ++j)
      lds[(i4 * 4 + j) * 17 + kp] = (uint32_t)f2b(a0[j]) | ((uint32_t)f2b(a1[j]) << 16);
  }
  __syncthreads();
  #pragma unroll
  for (int r = 0; r < 4; ++r) {
    const int idx = r * 256 + t;
    const int il = idx >> 2, q4 = idx & 3;
    uint4 o;
    o.x = lds[il * 17 + q4 * 4 + 0];
    o.y = lds[il * 17 + q4 * 4 + 1];
    o.z = lds[il * 17 + q4 * 4 + 2];
    o.w = lds[il * 17 + q4 * 4 + 3];
    *(uint4*)(D + (size_t)il * K + q4 * 8) = o;
  }
}

// ============ 256x256 grouped GEMM, BK=32, 4-stage pipeline, counted vmcnt ===
// LDS swizzle (bijective, rule 21): granule G in a stage maps to logical
// (row, g): line=G>>3, p=G&7, q=p^(line&7), row=2*line+(q>>2), g=q&3.
// Staging keeps LDS dest linear (gld16) and inverse-swizzles the global source;
// compute reads at line=row>>1, p=((row&1)*4+g)^(line&7).
// Operand convention (matches epilogue!): A-frags = WEIGHT rows (nt tile,
// D reg-dim), B-frags = token rows (mt tile, D col=lane&15).
// Per wave per tile: 8 A-frags + 4 B-frags (ds_read_b128), 32 MFMA.
// Pipeline: stages t,t+1,t+2 in flight; issue t+3, wait vmcnt(12) (never 0).

// ---------------- grouped GEMM1: h = silu(W1T-tile x Xg-tile + b1) -----------
__global__ __launch_bounds__(512, 2) void gemm1_k(
    const unsigned short* __restrict__ xb, const unsigned short* __restrict__ w1t,
    const float* __restrict__ b1, const int* __restrict__ meta,
    const int* __restrict__ ltok, unsigned short* __restrict__ h)
{
  const int wg = blockIdx.x;                       // 1152 = 72*16, %8==0
  const int id = (wg & 7) * (1152 / 8) + (wg >> 3);
  const int mt = id >> 4, nt = id & 15;
  if (mt * 256 >= meta[24]) return;
  int e = 0;
  #pragma unroll
  for (int i = 1; i < 8; ++i) if (meta[16 + i] <= mt * 256) e = i;

  extern __shared__ char lds[];                    // 4 stages x (16KB A + 16KB B)
  const int t = threadIdx.x;
  const int w = t >> 6, l = t & 63;
  const int wm = w & 1, wn = w >> 1;

  // staging sources: thread covers granules G = c*512 + w*64 + l, c in {0,1}
  // A = W1T rows (i-dim, nt tile); B = gathered token rows (mt tile)
  const unsigned short* asrc[2]; const unsigned short* bsrc[2];
  #pragma unroll
  for (int c = 0; c < 2; ++c) {
    const int G = c * 512 + w * 64 + l;
    const int line = G >> 3, q = (G & 7) ^ (line & 7);
    const int row = 2 * line + (q >> 2), g = q & 3;
    asrc[c] = w1t + ((size_t)e * IDIM + nt * 256 + row) * HDIM + g * 8;
    int tok = ltok[mt * 256 + row]; if (tok < 0) tok = 0;
    bsrc[c] = xb + (size_t)tok * HDIM + g * 8;
  }

  const int lr = l & 15, lg = l >> 4;
  const int p_r = (((lr & 1) << 2) + lg) ^ (lr >> 1);
  const int aoff = (wm * 64 + (lr >> 1)) * 128 + p_r * 16;
  const int boff = (wn * 32 + (lr >> 1)) * 128 + p_r * 16;

  f32x4 acc[8][4] = {};

  auto STAGE = [&](int tile) {
    const int ks = tile * 32;
    char* ab = lds + (tile & 3) * 32768;
    char* bb = ab + 16384;
    #pragma unroll
    for (int c = 0; c < 2; ++c) {
      gld16(asrc[c] + ks, ab + (c * 512 + w * 64) * 16);
      gld16(bsrc[c] + ks, bb + (c * 512 + w * 64) * 16);
    }
  };

  STAGE(0); STAGE(1); STAGE(2);
  const int NT = HDIM / 32;                        // 32
  for (int kt = 0; kt < NT; ++kt) {
    if (kt + 3 < NT) {
      STAGE(kt + 3);
      asm volatile("s_waitcnt vmcnt(12)" ::: "memory");
    } else if (kt + 2 < NT) {
      asm volatile("s_waitcnt vmcnt(8)" ::: "memory");
    } else if (kt + 1 < NT) {
      asm volatile("s_waitcnt vmcnt(4)" ::: "memory");
    } else {
      asm volatile("s_waitcnt vmcnt(0)" ::: "memory");
    }
    __builtin_amdgcn_s_barrier();
    const char* ab = lds + (kt & 3) * 32768;
    const char* bb = ab + 16384;
    bf16x8 af[8], bf[4];
    #pragma unroll
    for (int fm = 0; fm < 8; ++fm) af[fm] = *(const bf16x8*)(ab + aoff + fm * 1024);
    #pragma unroll
    for (int fn = 0; fn < 4; ++fn) bf[fn] = *(const bf16x8*)(bb + boff + fn * 1024);
    __builtin_amdgcn_s_setprio(1);
    #pragma unroll
    for (int fm = 0; fm < 8; ++fm)
      #pragma unroll
      for (int fn = 0; fn < 4; ++fn)
        acc[fm][fn] = __builtin_amdgcn_mfma_f32_16x16x32_bf16(af[fm], bf[fn], acc[fm][fn], 0, 0, 0);
    __builtin_amdgcn_s_setprio(0);
    __builtin_amdgcn_s_barrier();
  }

  // epilogue: +b1, silu, packed ushort4 stores (D reg-dim = i, col-dim = token)
  const int lg4 = lg * 4;
  #pragma unroll
  for (int fm = 0; fm < 8; ++fm) {
    const int ib = nt * 256 + wm * 128 + fm * 16 + lg4;
    const float4 b1v = *(const float4*)(b1 + e * IDIM + ib);
    #pragma unroll
    for (int fn = 0; fn < 4; ++fn) {
      const int trow = mt * 256 + wn * 64 + fn * 16 + lr;
      const float v0 = acc[fm][fn][0] + b1v.x;
      const float v1 = acc[fm][fn][1] + b1v.y;
      const float v2 = acc[fm][fn][2] + b1v.z;
      const float v3 = acc[fm][fn][3] + b1v.w;
      ushort4 st;
      st.x = f2b(v0 / (1.f + __expf(-v0)));
      st.y = f2b(v1 / (1.f + __expf(-v1)));
      st.z = f2b(v2 / (1.f + __expf(-v2)));
      st.w = f2b(v3 / (1.f + __expf(-v3)));
      *(ushort4*)(h + (size_t)trow * IDIM + ib) = st;
    }
  }
}

// ---------------- grouped GEMM2: y = h @ W2T^T (float4 stores) ----------------
__global__ __launch_bounds__(512, 2) void gemm2_k(
    const unsigned short* __restrict__ h, const unsigned short* __restrict__ w2t,
    const int* __restrict__ meta, float* __restrict__ y)
{
  const int wg = blockIdx.x;                       // 288 = 72*4, %8==0
  const int id = (wg & 7) * (288 / 8) + (wg >> 3);
  const int mt = id >> 2, nt = id & 3;
  if (mt * 256 >= meta[24]) return;
  int e = 0;
  #pragma unroll
  for (int i = 1; i < 8; ++i) if (meta[16 + i] <= mt * 256) e = i;

  extern __shared__ char lds[];
  const int t = threadIdx.x;
  const int w = t >> 6, l = t & 63;
  const int wm = w & 1, wn = w >> 1;

  // A = W2T rows (hcol-dim, nt tile); B = h token rows (mt tile)
  const unsigned short* asrc[2]; const unsigned short* bsrc[2];
  #pragma unroll
  for (int c = 0; c < 2; ++c) {
    const int G = c * 512 + w * 64 + l;
    const int line = G >> 3, q = (G & 7) ^ (line & 7);
    const int row = 2 * line + (q >> 2), g = q & 3;
    asrc[c] = w2t + ((size_t)e * HDIM + nt * 256 + row) * IDIM + g * 8;
    bsrc[c] = h + (size_t)(mt * 256 + row) * IDIM + g * 8;
  }

  const int lr = l & 15, lg = l >> 4;
  const int p_r = (((lr & 1) << 2) + lg) ^ (lr >> 1);
  const int aoff = (wm * 64 + (lr >> 1)) * 128 + p_r * 16;
  const int boff = (wn * 32 + (lr >> 1)) * 128 + p_r * 16;

  f32x4 acc[8][4] = {};

  auto STAGE = [&](int tile) {
    const int ks = tile * 32;
    char* ab = lds + (tile & 3) * 32768;
    char* bb = ab + 16384;
    #pragma unroll
    for (int c = 0; c < 2; ++c) {
      gld16(asrc[c] + ks, ab + (c * 512 + w * 64) * 16);
      gld16(bsrc[c] + ks, bb + (c * 512 + w * 64) * 16);
    }
  };

  STAGE(0); STAGE(1); STAGE(2);
  const int NT = IDIM / 32;                        // 128
  for (int kt = 0; kt < NT; ++kt) {
    if (kt + 3 < NT) {
      STAGE(kt + 3);
      asm volatile("s_waitcnt vmcnt(12)" ::: "memory");
    } else if (kt + 2 < NT) {
      asm volatile("s_waitcnt vmcnt(8)" ::: "memory");
    } else if (kt + 1 < NT) {
      asm volatile("s_waitcnt vmcnt(4)" ::: "memory");
    } else {
      asm volatile("s_waitcnt vmcnt(0)" ::: "memory");
    }
    __builtin_amdgcn_s_barrier();
    const char* ab = lds + (kt & 3) * 32768;
    const char* bb = ab + 16384;
    bf16x8 af[8], bf[4];
    #pragma unroll
    for (int fm = 0; fm < 8; ++fm) af[fm] = *(const bf16x8*)(ab + aoff + fm * 1024);
    #pragma unroll
    for (int fn = 0; fn < 4; ++fn) bf[fn] = *(const bf16x8*)(bb + boff + fn * 1024);
    __builtin_amdgcn_s_setprio(1);
    #pragma unroll
    for (int fm = 0; fm < 8; ++fm)
      #pragma unroll
      for (int fn = 0; fn < 4; ++fn)
        acc[fm][fn] = __builtin_amdgcn_mfma_f32_16x16x32_bf16(af[fm], bf[fn], acc[fm][fn], 0, 0, 0);
    __builtin_amdgcn_s_setprio(0);
    __builtin_amdgcn_s_barrier();
  }

  // epilogue: coalesced float4 stores (D reg-dim = hcol, col-dim = token)
  const int lg4 = lg * 4;
  #pragma unroll
  for (int fm = 0; fm < 8; ++fm) {
    const int colb = nt * 256 + wm * 128 + fm * 16 + lg4;
    #pragma unroll
    for (int fn = 0; fn < 4; ++fn) {
      const int row = mt * 256 + wn * 64 + fn * 16 + lr;
      float4 st;
      st.x = acc[fm][fn][0]; st.y = acc[fm][fn][1];
      st.z = acc[fm][fn][2]; st.w = acc[fm][fn][3];
      *(float4*)(y + (size_t)row * HDIM + colb) = st;
    }
  }
}

// ---------------- combine: out[t] = w0*(y[p0]+b2[e0]) + w1*(y[p1]+b2[e1]) ----------------
__global__ __launch_bounds__(256, 4) void combine_k(
    const float* __restrict__ y, const float* __restrict__ b2,
    const int* __restrict__ t2e, const float* __restrict__ t2w,
    const int* __restrict__ t2p, float* __restrict__ out)
{
  const int t = blockIdx.x * 4 + (threadIdx.x >> 6);
  const int l = threadIdx.x & 63;
  const int e0 = t2e[t * 2], e1 = t2e[t * 2 + 1];
  const float w0 = t2w[t * 2], w1v = t2w[t * 2 + 1];
  const int p0 = t2p[t * 2], p1 = t2p[t * 2 + 1];
  const float* y0 = y + (size_t)p0 * HDIM;
  const float* y1 = y + (size_t)p1 * HDIM;
  const float* bb0 = b2 + e0 * HDIM;
  const float* bb1 = b2 + e1 * HDIM;
  float* o = out + (size_t)t * HDIM;
  #pragma unroll
  for (int j = 0; j < 4; ++j) {
    const int c = j * 256 + l * 4;
    const float4 a = *(const float4*)(y0 + c);
    const float4 b = *(const float4*)(y1 + c);
    const float4 c0 = *(const float4*)(bb0 + c);
    const float4 c1 = *(const float4*)(bb1 + c);
    float4 r;
    r.x = w0 * (a.x + c0.x) + w1v * (b.x + c1.x);
    r.y = w0 * (a.y + c0.y) + w1v * (b.y + c1.y);
    r.z = w0 * (a.z + c0.z) + w1v * (b.z + c1.z);
    r.w = w0 * (a.w + c0.w) + w1v * (b.w + c1.w);
    *(float4*)(o + c) = r;
  }
}

__global__ void sentinel_k(float* out) { out[0] = 1.0e6f; }

// ---------------- launcher ----------------
extern "C" void kernel_launch(void* const* d_in, const int* in_sizes, int n_in,
                              void* d_out, int out_size, void* d_ws, size_t ws_size,
                              hipStream_t stream)
{
  (void)in_sizes; (void)n_in; (void)out_size;
  const float* x  = (const float*)d_in[0];
  const float* wr = (const float*)d_in[1];
  const float* w1 = (const float*)d_in[2];
  const float* b1 = (const float*)d_in[3];
  const float* w2 = (const float*)d_in[4];
  const float* b2 = (const float*)d_in[5];
  float* out = (float*)d_out;
  char* ws = (char*)d_ws;

  if (ws_size < WS_NEED) { sentinel_k<<<1, 1, 0, stream>>>(out); return; }

  unsigned short* xb  = (unsigned short*)(ws);                 // 16.78 MB
  unsigned short* w1t = (unsigned short*)(ws + 16777216);      // 67.1 MB
  unsigned short* w2t = (unsigned short*)(ws + 83886080);      // 67.1 MB
  unsigned short* h   = (unsigned short*)(ws + 150994944);     // 151.0 MB
  int*   t2e  = (int*)(ws + 301989888);
  float* t2w  = (float*)(ws + 302055424);
  int*   ltok = (int*)(ws + 302120960);
  int*   t2p  = (int*)(ws + 302194688);
  int*   meta = (int*)(ws + 302260224);
  // y aliases xb+w1t (both dead after gemm1): PMAX*HDIM*4 = 75.5MB < 83.9MB
  float* y    = (float*)(ws);

  // allow 128KB dynamic LDS on the GEMMs (non-stream op; graph-capture safe)
  hipFuncSetAttribute((const void*)gemm1_k, hipFuncAttributeMaxDynamicSharedMemorySize, 131072);
  hipFuncSetAttribute((const void*)gemm2_k, hipFuncAttributeMaxDynamicSharedMemorySize, 131072);

  router_k<<<TTOK / 4, 256, 0, stream>>>(x, wr, xb, t2e, t2w);
  packT_k<<<NEXP * (HDIM / 32) * (IDIM / 256), 256, 0, stream>>>(w1, w1t, HDIM, IDIM);
  packT_k<<<NEXP * (IDIM / 32) * (HDIM / 256), 256, 0, stream>>>(w2, w2t, IDIM, HDIM);
  count_k<<<1, 512, 0, stream>>>(t2e, meta);
  scatter_k<<<NEXP, 256, 0, stream>>>(t2e, meta, ltok, t2p);

  gemm1_k<<<MT_MAX * (IDIM / 256), 512, 131072, stream>>>(xb, w1t, b1, meta, ltok, h);
  gemm2_k<<<MT_MAX * (HDIM / 256), 512, 131072, stream>>>(h, w2t, meta, y);
  combine_k<<<TTOK / 4, 256, 0, stream>>>(y, b2, t2e, t2w, t2p, out);
}

// Round 6
// 550.376 us; speedup vs baseline: 1.7906x; 1.1598x over previous
//
#include <hip/hip_runtime.h>
#include <cstdint>
#include <cstddef>

// ---------------- problem constants ----------------
#define TTOK 8192          // B*S tokens
#define HDIM 1024
#define IDIM 4096
#define NEXP 8
#define PMAX 18432         // 16384 + 8*256 (segment padding to 256)
#define WS_NEED 302260352ULL

// GEMM geometry: BM=256 tokens, BN=128 outputs, BK=32, 512 threads (8 waves),
// wave tile 64x64, 3-stage LDS pipeline (24KB/stage -> 72KB -> 2 blocks/CU).
#define STG 24576

typedef __attribute__((ext_vector_type(8))) short bf16x8;
typedef __attribute__((ext_vector_type(4))) float f32x4;

#define AS3 __attribute__((address_space(3)))
#define AS1 __attribute__((address_space(1)))

__device__ __forceinline__ void gld16(const void* g, void* s) {
  // async global->LDS, 16B/lane; LDS dest is wave-uniform base (+lane*16 in HW)
  __builtin_amdgcn_global_load_lds((const AS1 void*)g, (AS3 void*)s, 16, 0, 0);
}

__device__ __forceinline__ unsigned short f2b(float f) {
  unsigned u = __builtin_bit_cast(unsigned, f);
  unsigned r = ((u >> 16) & 1u) + 0x7FFFu;   // RNE
  return (unsigned short)((u + r) >> 16);
}

// meta layout (ints): [0..7] counts, [16..23] offs, meta[24]=padded total
// ---------------- router: logits, top2, x->bf16 (no atomics) ----------------
__global__ __launch_bounds__(256, 2) void router_k(
    const float* __restrict__ x, const float* __restrict__ wr,
    unsigned short* __restrict__ xb, int* __restrict__ t2e,
    float* __restrict__ t2w)
{
  const int t = blockIdx.x * 4 + (threadIdx.x >> 6);
  const int l = threadIdx.x & 63;
  const float* xr = x + (size_t)t * HDIM;
  float acc[8] = {0.f,0.f,0.f,0.f,0.f,0.f,0.f,0.f};
  #pragma unroll
  for (int j = 0; j < 4; ++j) {
    const int base = j * 256 + l * 4;
    const float4 xv = *(const float4*)(xr + base);
    const float xa[4] = {xv.x, xv.y, xv.z, xv.w};
    ushort4 ub;
    ub.x = f2b(xa[0]); ub.y = f2b(xa[1]); ub.z = f2b(xa[2]); ub.w = f2b(xa[3]);
    *(ushort4*)(xb + (size_t)t * HDIM + base) = ub;
    #pragma unroll
    for (int ii = 0; ii < 4; ++ii) {
      const float4 w0 = *(const float4*)(wr + (size_t)(base + ii) * 8);
      const float4 w1 = *(const float4*)(wr + (size_t)(base + ii) * 8 + 4);
      acc[0] += xa[ii] * w0.x; acc[1] += xa[ii] * w0.y;
      acc[2] += xa[ii] * w0.z; acc[3] += xa[ii] * w0.w;
      acc[4] += xa[ii] * w1.x; acc[5] += xa[ii] * w1.y;
      acc[6] += xa[ii] * w1.z; acc[7] += xa[ii] * w1.w;
    }
  }
  #pragma unroll
  for (int e = 0; e < 8; ++e) {
    float v = acc[e];
    #pragma unroll
    for (int off = 32; off > 0; off >>= 1) v += __shfl_xor(v, off);
    acc[e] = v;
  }
  if (l == 0) {
    float l0 = -1e30f; int i0 = 0;
    #pragma unroll
    for (int e = 0; e < 8; ++e) if (acc[e] > l0) { l0 = acc[e]; i0 = e; }
    float l1 = -1e30f; int i1 = (i0 == 0) ? 1 : 0;
    #pragma unroll
    for (int e = 0; e < 8; ++e) if (e != i0 && acc[e] > l1) { l1 = acc[e]; i1 = e; }
    // renormalized top2 softmax == sigmoid of gap
    const float w0 = 1.f / (1.f + expf(l1 - l0));
    t2e[t * 2] = i0; t2e[t * 2 + 1] = i1;
    t2w[t * 2] = w0; t2w[t * 2 + 1] = 1.f - w0;
  }
}

// ---------------- count: ballot histogram, offsets (1 block, no atomics) ----
__global__ void count_k(const int* __restrict__ t2e, int* __restrict__ meta) {
  const int t = threadIdx.x, w = t >> 6, l = t & 63;
  int cnt[8] = {0,0,0,0,0,0,0,0};
  for (int c = 0; c < 16; ++c) {               // 8 waves x 16 x 64 = 8192
    const int tok = (w * 16 + c) * 64 + l;
    const int e0 = t2e[2 * tok], e1 = t2e[2 * tok + 1];
    #pragma unroll
    for (int e = 0; e < 8; ++e)
      cnt[e] += __popcll(__ballot(e0 == e)) + __popcll(__ballot(e1 == e));
  }
  __shared__ int part[8][8];
  if (l == 0) {
    #pragma unroll
    for (int e = 0; e < 8; ++e) part[w][e] = cnt[e];
  }
  __syncthreads();
  if (t == 0) {
    int off = 0;
    #pragma unroll
    for (int e = 0; e < 8; ++e) {
      int s = 0;
      #pragma unroll
      for (int w2 = 0; w2 < 8; ++w2) s += part[w2][e];
      meta[e] = s; meta[16 + e] = off; off += (s + 255) & ~255;
    }
    meta[24] = off;
  }
}

// ---------------- scatter: deterministic per-expert prefix scan -------------
__global__ void scatter_k(const int* __restrict__ t2e, const int* __restrict__ meta,
                          int* __restrict__ ltok, int* __restrict__ t2p)
{
  const int e = blockIdx.x;
  const int t = threadIdx.x, w = t >> 6, l = t & 63;
  const int off = meta[16 + e];
  const int cnt = meta[e];
  __shared__ int wsum[4];
  __shared__ int base;
  if (t == 0) base = 0;
  __syncthreads();
  const unsigned long long lt = (1ULL << l) - 1ULL;
  for (int c = 0; c < TTOK / 256; ++c) {
    const int tok = c * 256 + t;
    const bool m0 = (t2e[2 * tok] == e);
    const bool m1 = (t2e[2 * tok + 1] == e);
    const unsigned long long b0 = __ballot(m0);
    const unsigned long long b1 = __ballot(m1);
    const int n0 = __popcll(b0), n1 = __popcll(b1);
    const int r0 = __popcll(b0 & lt);
    const int r1 = n0 + __popcll(b1 & lt);
    if (l == 0) wsum[w] = n0 + n1;
    __syncthreads();
    int wb = base;
    #pragma unroll
    for (int i = 0; i < 4; ++i) if (i < w) wb += wsum[i];
    const int tot = wsum[0] + wsum[1] + wsum[2] + wsum[3];
    __syncthreads();
    if (t == 0) base += tot;
    if (m0) { const int p = off + wb + r0; ltok[p] = tok; t2p[2 * tok] = p; }
    if (m1) { const int p = off + wb + r1; ltok[p] = tok; t2p[2 * tok + 1] = p; }
    __syncthreads();
  }
  const int padded = (cnt + 255) & ~255;
  for (int i = cnt + t; i < padded; i += 256) ltok[off + i] = -1;
}

// ---------------- transpose-pack W[e][K][N] fp32 -> WT[e][N][K] bf16 ----------------
__global__ __launch_bounds__(256, 2) void packT_k(const float* __restrict__ src,
                                                  unsigned short* __restrict__ dst,
                                                  int K, int N)
{
  const int tiles_n = N >> 8, tiles_k = K >> 5;
  const int bid = blockIdx.x;
  const int e = bid / (tiles_k * tiles_n);
  const int rem = bid % (tiles_k * tiles_n);
  const int kt = rem / tiles_n, it = rem % tiles_n;
  const float* S = src + (size_t)e * K * N + (size_t)kt * 32 * N + (size_t)it * 256;
  unsigned short* D = dst + (size_t)e * N * K + (size_t)it * 256 * K + (size_t)kt * 32;
  __shared__ uint32_t lds[256 * 17];
  const int t = threadIdx.x;
  #pragma unroll
  for (int q = 0; q < 4; ++q) {
    const int task = q * 256 + t;
    const int i4 = task & 63, kp = task >> 6;
    const float* p0 = S + (size_t)(2 * kp) * N + i4 * 4;
    const float4 r0 = *(const float4*)p0;
    const float4 r1 = *(const float4*)(p0 + N);
    const float a0[4] = {r0.x, r0.y, r0.z, r0.w};
    const float a1[4] = {r1.x, r1.y, r1.z, r1.w};
    #pragma unroll
    for (int j = 0; j < 4; ++j)
      lds[(i4 * 4 + j) * 17 + kp] = (uint32_t)f2b(a0[j]) | ((uint32_t)f2b(a1[j]) << 16);
  }
  __syncthreads();
  #pragma unroll
  for (int r = 0; r < 4; ++r) {
    const int idx = r * 256 + t;
    const int il = idx >> 2, q4 = idx & 3;
    uint4 o;
    o.x = lds[il * 17 + q4 * 4 + 0];
    o.y = lds[il * 17 + q4 * 4 + 1];
    o.z = lds[il * 17 + q4 * 4 + 2];
    o.w = lds[il * 17 + q4 * 4 + 3];
    *(uint4*)(D + (size_t)il * K + q4 * 8) = o;
  }
}

// ============ grouped GEMM, 256(tok) x 128(out) tile, BK=32, 3-stage ========
// LDS swizzle (bijective, rule 21): granule G in a tile maps to logical
// (row, g): line=G>>3, p=G&7, q=p^(line&7), row=2*line+(q>>2), g=q&3.
// Staging keeps LDS dest linear (gld16) and inverse-swizzles the global source;
// compute reads at line=row>>1, p=((row&1)*4+g)^(line&7).
// Stage layout: A (weights, 128 rows, 8KB) at +0; B (tokens, 256 rows, 16KB)
// at +8192. 3 loads/thread/stage. Waves: 2 (N) x 4 (M); wave tile 64x64.
// Pipeline: stages t,t+1 in flight; issue t+2, wait vmcnt(6) (never 0 mid-loop).

// ---------------- grouped GEMM1: h = silu(W1T-tile x Xg-tile + b1) -----------
__global__ __launch_bounds__(512, 4) void gemm1_k(
    const unsigned short* __restrict__ xb, const unsigned short* __restrict__ w1t,
    const float* __restrict__ b1, const int* __restrict__ meta,
    const int* __restrict__ ltok, unsigned short* __restrict__ h)
{
  const int wg = blockIdx.x;                       // 2304 = 72*32, %8==0
  const int id = (wg & 7) * (2304 / 8) + (wg >> 3);
  const int mt = id >> 5, nt = id & 31;
  if (mt * 256 >= meta[24]) return;
  int e = 0;
  #pragma unroll
  for (int i = 1; i < 8; ++i) if (meta[16 + i] <= mt * 256) e = i;

  extern __shared__ char lds[];                    // 3 stages x 24KB
  const int t = threadIdx.x;
  const int w = t >> 6, l = t & 63;
  const int wn = w & 1, wm = w >> 1;               // 2 N-cols x 4 M-rows of waves

  // A source (1 granule/thread): G = t   (W1T rows = i-dim, nt tile)
  const unsigned short* asrc;
  {
    const int G = t;
    const int line = G >> 3, q = (G & 7) ^ (line & 7);
    const int row = 2 * line + (q >> 2), g = q & 3;
    asrc = w1t + ((size_t)e * IDIM + nt * 128 + row) * HDIM + g * 8;
  }
  // B sources (2 granules/thread): G = c*512 + t  (gathered token rows, mt tile)
  const unsigned short* bsrc[2];
  #pragma unroll
  for (int c = 0; c < 2; ++c) {
    const int G = c * 512 + t;
    const int line = G >> 3, q = (G & 7) ^ (line & 7);
    const int row = 2 * line + (q >> 2), g = q & 3;
    int tok = ltok[mt * 256 + row]; if (tok < 0) tok = 0;
    bsrc[c] = xb + (size_t)tok * HDIM + g * 8;
  }

  const int lr = l & 15, lg = l >> 4;
  const int p_r = (((lr & 1) << 2) + lg) ^ (lr >> 1);
  const int aoff = (wn * 32 + (lr >> 1)) * 128 + p_r * 16;           // A base row wn*64
  const int boff = 8192 + (wm * 32 + (lr >> 1)) * 128 + p_r * 16;    // B base row wm*64

  f32x4 acc[4][4] = {};

  auto STAGE = [&](int tile) {
    const int ks = tile * 32;
    char* sb = lds + (tile % 3) * STG;
    gld16(asrc + ks, sb + w * 1024);
    gld16(bsrc[0] + ks, sb + 8192 + w * 1024);
    gld16(bsrc[1] + ks, sb + 16384 + w * 1024);
  };

  STAGE(0); STAGE(1);
  const int NT = HDIM / 32;                        // 32
  for (int kt = 0; kt < NT; ++kt) {
    if (kt + 2 < NT) {
      STAGE(kt + 2);
      asm volatile("s_waitcnt vmcnt(6)" ::: "memory");
    } else if (kt + 1 < NT) {
      asm volatile("s_waitcnt vmcnt(3)" ::: "memory");
    } else {
      asm volatile("s_waitcnt vmcnt(0)" ::: "memory");
    }
    __builtin_amdgcn_s_barrier();
    const char* ab = lds + (kt % 3) * STG;
    bf16x8 af[4], bf[4];
    #pragma unroll
    for (int fm = 0; fm < 4; ++fm) af[fm] = *(const bf16x8*)(ab + aoff + fm * 1024);
    #pragma unroll
    for (int fn = 0; fn < 4; ++fn) bf[fn] = *(const bf16x8*)(ab + boff + fn * 1024);
    __builtin_amdgcn_s_setprio(1);
    #pragma unroll
    for (int fm = 0; fm < 4; ++fm)
      #pragma unroll
      for (int fn = 0; fn < 4; ++fn)
        acc[fm][fn] = __builtin_amdgcn_mfma_f32_16x16x32_bf16(af[fm], bf[fn], acc[fm][fn], 0, 0, 0);
    __builtin_amdgcn_s_setprio(0);
    __builtin_amdgcn_s_barrier();
  }

  // epilogue: +b1, silu, packed ushort4 stores (D reg-dim = i, col-dim = token)
  const int lg4 = lg * 4;
  #pragma unroll
  for (int fm = 0; fm < 4; ++fm) {
    const int ib = nt * 128 + wn * 64 + fm * 16 + lg4;
    const float4 b1v = *(const float4*)(b1 + e * IDIM + ib);
    #pragma unroll
    for (int fn = 0; fn < 4; ++fn) {
      const int trow = mt * 256 + wm * 64 + fn * 16 + lr;
      const float v0 = acc[fm][fn][0] + b1v.x;
      const float v1 = acc[fm][fn][1] + b1v.y;
      const float v2 = acc[fm][fn][2] + b1v.z;
      const float v3 = acc[fm][fn][3] + b1v.w;
      ushort4 st;
      st.x = f2b(v0 / (1.f + __expf(-v0)));
      st.y = f2b(v1 / (1.f + __expf(-v1)));
      st.z = f2b(v2 / (1.f + __expf(-v2)));
      st.w = f2b(v3 / (1.f + __expf(-v3)));
      *(ushort4*)(h + (size_t)trow * IDIM + ib) = st;
    }
  }
}

// ---------------- grouped GEMM2: y = h @ W2T^T (float4 stores) ----------------
__global__ __launch_bounds__(512, 4) void gemm2_k(
    const unsigned short* __restrict__ h, const unsigned short* __restrict__ w2t,
    const int* __restrict__ meta, float* __restrict__ y)
{
  const int wg = blockIdx.x;                       // 576 = 72*8, %8==0
  const int id = (wg & 7) * (576 / 8) + (wg >> 3);
  const int mt = id >> 3, nt = id & 7;
  if (mt * 256 >= meta[24]) return;
  int e = 0;
  #pragma unroll
  for (int i = 1; i < 8; ++i) if (meta[16 + i] <= mt * 256) e = i;

  extern __shared__ char lds[];
  const int t = threadIdx.x;
  const int w = t >> 6, l = t & 63;
  const int wn = w & 1, wm = w >> 1;

  // A = W2T rows (hcol-dim, nt tile); B = h token rows (mt tile)
  const unsigned short* asrc;
  {
    const int G = t;
    const int line = G >> 3, q = (G & 7) ^ (line & 7);
    const int row = 2 * line + (q >> 2), g = q & 3;
    asrc = w2t + ((size_t)e * HDIM + nt * 128 + row) * IDIM + g * 8;
  }
  const unsigned short* bsrc[2];
  #pragma unroll
  for (int c = 0; c < 2; ++c) {
    const int G = c * 512 + t;
    const int line = G >> 3, q = (G & 7) ^ (line & 7);
    const int row = 2 * line + (q >> 2), g = q & 3;
    bsrc[c] = h + (size_t)(mt * 256 + row) * IDIM + g * 8;
  }

  const int lr = l & 15, lg = l >> 4;
  const int p_r = (((lr & 1) << 2) + lg) ^ (lr >> 1);
  const int aoff = (wn * 32 + (lr >> 1)) * 128 + p_r * 16;
  const int boff = 8192 + (wm * 32 + (lr >> 1)) * 128 + p_r * 16;

  f32x4 acc[4][4] = {};

  auto STAGE = [&](int tile) {
    const int ks = tile * 32;
    char* sb = lds + (tile % 3) * STG;
    gld16(asrc + ks, sb + w * 1024);
    gld16(bsrc[0] + ks, sb + 8192 + w * 1024);
    gld16(bsrc[1] + ks, sb + 16384 + w * 1024);
  };

  STAGE(0); STAGE(1);
  const int NT = IDIM / 32;                        // 128
  for (int kt = 0; kt < NT; ++kt) {
    if (kt + 2 < NT) {
      STAGE(kt + 2);
      asm volatile("s_waitcnt vmcnt(6)" ::: "memory");
    } else if (kt + 1 < NT) {
      asm volatile("s_waitcnt vmcnt(3)" ::: "memory");
    } else {
      asm volatile("s_waitcnt vmcnt(0)" ::: "memory");
    }
    __builtin_amdgcn_s_barrier();
    const char* ab = lds + (kt % 3) * STG;
    bf16x8 af[4], bf[4];
    #pragma unroll
    for (int fm = 0; fm < 4; ++fm) af[fm] = *(const bf16x8*)(ab + aoff + fm * 1024);
    #pragma unroll
    for (int fn = 0; fn < 4; ++fn) bf[fn] = *(const bf16x8*)(ab + boff + fn * 1024);
    __builtin_amdgcn_s_setprio(1);
    #pragma unroll
    for (int fm = 0; fm < 4; ++fm)
      #pragma unroll
      for (int fn = 0; fn < 4; ++fn)
        acc[fm][fn] = __builtin_amdgcn_mfma_f32_16x16x32_bf16(af[fm], bf[fn], acc[fm][fn], 0, 0, 0);
    __builtin_amdgcn_s_setprio(0);
    __builtin_amdgcn_s_barrier();
  }

  // epilogue: coalesced float4 stores (D reg-dim = hcol, col-dim = token)
  const int lg4 = lg * 4;
  #pragma unroll
  for (int fm = 0; fm < 4; ++fm) {
    const int colb = nt * 128 + wn * 64 + fm * 16 + lg4;
    #pragma unroll
    for (int fn = 0; fn < 4; ++fn) {
      const int row = mt * 256 + wm * 64 + fn * 16 + lr;
      float4 st;
      st.x = acc[fm][fn][0]; st.y = acc[fm][fn][1];
      st.z = acc[fm][fn][2]; st.w = acc[fm][fn][3];
      *(float4*)(y + (size_t)row * HDIM + colb) = st;
    }
  }
}

// ---------------- combine: out[t] = w0*(y[p0]+b2[e0]) + w1*(y[p1]+b2[e1]) ----------------
__global__ __launch_bounds__(256, 4) void combine_k(
    const float* __restrict__ y, const float* __restrict__ b2,
    const int* __restrict__ t2e, const float* __restrict__ t2w,
    const int* __restrict__ t2p, float* __restrict__ out)
{
  const int t = blockIdx.x * 4 + (threadIdx.x >> 6);
  const int l = threadIdx.x & 63;
  const int e0 = t2e[t * 2], e1 = t2e[t * 2 + 1];
  const float w0 = t2w[t * 2], w1v = t2w[t * 2 + 1];
  const int p0 = t2p[t * 2], p1 = t2p[t * 2 + 1];
  const float* y0 = y + (size_t)p0 * HDIM;
  const float* y1 = y + (size_t)p1 * HDIM;
  const float* bb0 = b2 + e0 * HDIM;
  const float* bb1 = b2 + e1 * HDIM;
  float* o = out + (size_t)t * HDIM;
  #pragma unroll
  for (int j = 0; j < 4; ++j) {
    const int c = j * 256 + l * 4;
    const float4 a = *(const float4*)(y0 + c);
    const float4 b = *(const float4*)(y1 + c);
    const float4 c0 = *(const float4*)(bb0 + c);
    const float4 c1 = *(const float4*)(bb1 + c);
    float4 r;
    r.x = w0 * (a.x + c0.x) + w1v * (b.x + c1.x);
    r.y = w0 * (a.y + c0.y) + w1v * (b.y + c1.y);
    r.z = w0 * (a.z + c0.z) + w1v * (b.z + c1.z);
    r.w = w0 * (a.w + c0.w) + w1v * (b.w + c1.w);
    *(float4*)(o + c) = r;
  }
}

__global__ void sentinel_k(float* out) { out[0] = 1.0e6f; }

// ---------------- launcher ----------------
extern "C" void kernel_launch(void* const* d_in, const int* in_sizes, int n_in,
                              void* d_out, int out_size, void* d_ws, size_t ws_size,
                              hipStream_t stream)
{
  (void)in_sizes; (void)n_in; (void)out_size;
  const float* x  = (const float*)d_in[0];
  const float* wr = (const float*)d_in[1];
  const float* w1 = (const float*)d_in[2];
  const float* b1 = (const float*)d_in[3];
  const float* w2 = (const float*)d_in[4];
  const float* b2 = (const float*)d_in[5];
  float* out = (float*)d_out;
  char* ws = (char*)d_ws;

  if (ws_size < WS_NEED) { sentinel_k<<<1, 1, 0, stream>>>(out); return; }

  unsigned short* xb  = (unsigned short*)(ws);                 // 16.78 MB
  unsigned short* w1t = (unsigned short*)(ws + 16777216);      // 67.1 MB
  unsigned short* w2t = (unsigned short*)(ws + 83886080);      // 67.1 MB
  unsigned short* h   = (unsigned short*)(ws + 150994944);     // 151.0 MB
  int*   t2e  = (int*)(ws + 301989888);
  float* t2w  = (float*)(ws + 302055424);
  int*   ltok = (int*)(ws + 302120960);
  int*   t2p  = (int*)(ws + 302194688);
  int*   meta = (int*)(ws + 302260224);
  // y aliases xb+w1t (both dead after gemm1): PMAX*HDIM*4 = 75.5MB < 83.9MB
  float* y    = (float*)(ws);

  // allow 72KB dynamic LDS on the GEMMs (non-stream op; graph-capture safe)
  hipFuncSetAttribute((const void*)gemm1_k, hipFuncAttributeMaxDynamicSharedMemorySize, 3 * STG);
  hipFuncSetAttribute((const void*)gemm2_k, hipFuncAttributeMaxDynamicSharedMemorySize, 3 * STG);

  router_k<<<TTOK / 4, 256, 0, stream>>>(x, wr, xb, t2e, t2w);
  packT_k<<<NEXP * (HDIM / 32) * (IDIM / 256), 256, 0, stream>>>(w1, w1t, HDIM, IDIM);
  packT_k<<<NEXP * (IDIM / 32) * (HDIM / 256), 256, 0, stream>>>(w2, w2t, IDIM, HDIM);
  count_k<<<1, 512, 0, stream>>>(t2e, meta);
  scatter_k<<<NEXP, 256, 0, stream>>>(t2e, meta, ltok, t2p);

  gemm1_k<<<72 * 32, 512, 3 * STG, stream>>>(xb, w1t, b1, meta, ltok, h);
  gemm2_k<<<72 * 8, 512, 3 * STG, stream>>>(h, w2t, meta, y);
  combine_k<<<TTOK / 4, 256, 0, stream>>>(y, b2, t2e, t2w, t2p, out);
}